// Round 8
// baseline (263.977 us; speedup 1.0000x reference)
//
#include <hip/hip_runtime.h>
#include <hip/hip_bf16.h>
#include <math.h>

#define DIV_UP(a,b) (((a)+(b)-1)/(b))

typedef __attribute__((ext_vector_type(8))) short short8v;
typedef __attribute__((ext_vector_type(4))) float f32x4;

__device__ __forceinline__ float bf_lo(unsigned u){ union{unsigned x; float f;} v; v.x = u << 16; return v.f; }
__device__ __forceinline__ float bf_hi(unsigned u){ union{unsigned x; float f;} v; v.x = u & 0xffff0000u; return v.f; }
__device__ __forceinline__ unsigned short f2bf(float f){
  union{float f; unsigned u;} v; v.f = f;
  unsigned r = v.u + 0x7fff + ((v.u >> 16) & 1);   // round-nearest-even
  return (unsigned short)(r >> 16);
}
__device__ __forceinline__ unsigned packbf(float a, float b){
  return (unsigned)f2bf(a) | ((unsigned)f2bf(b) << 16);
}
__device__ __forceinline__ float lrelu(float x){ return x > 0.f ? x : 0.2f*x; }

// ---------------- CSR build ----------------
__global__ void k_count_deg(const int* __restrict__ dst, int* __restrict__ deg, int E){
  int i = blockIdx.x*blockDim.x + threadIdx.x;
  if (i < E) atomicAdd(&deg[dst[i]], 1);
}

__global__ __launch_bounds__(256) void k_scan1(const int* __restrict__ deg,
                                               int* __restrict__ blocksum, int N){
  int b = blockIdx.x;
  int base = b*1024 + threadIdx.x*4;
  int s = 0;
  if (base + 3 < N){
    int4 v = *(const int4*)&deg[base];
    s = v.x + v.y + v.z + v.w;
  } else {
    for (int i = 0; i < 4; i++){ int idx = base + i; if (idx < N) s += deg[idx]; }
  }
  #pragma unroll
  for (int o = 32; o; o >>= 1) s += __shfl_down(s, o);
  __shared__ int ws[4];
  int wid = threadIdx.x >> 6, lane = threadIdx.x & 63;
  if (lane == 0) ws[wid] = s;
  __syncthreads();
  if (threadIdx.x == 0) blocksum[b] = ws[0] + ws[1] + ws[2] + ws[3];
}

__global__ void k_scan2(int* __restrict__ blocksum, int nb){
  int lane = threadIdx.x;  // 64 threads
  int carry = 0;
  for (int base = 0; base < nb; base += 64){
    int idx = base + lane;
    int orig = (idx < nb) ? blocksum[idx] : 0;
    int v = orig;
    #pragma unroll
    for (int o = 1; o < 64; o <<= 1){ int t = __shfl_up(v, o); if (lane >= o) v += t; }
    if (idx < nb) blocksum[idx] = carry + v - orig;   // exclusive
    carry += __shfl(v, 63);
  }
}

__global__ __launch_bounds__(256) void k_scan3(const int* __restrict__ deg,
                                               const int* __restrict__ blockoff,
                                               int* __restrict__ row_start,
                                               int* __restrict__ cursor, int N){
  int b = blockIdx.x;
  int base = b*1024 + threadIdx.x*4;
  int v[4];
  #pragma unroll
  for (int i = 0; i < 4; i++){ int idx = base + i; v[i] = (idx < N) ? deg[idx] : 0; }
  int s = v[0] + v[1] + v[2] + v[3];
  int lane = threadIdx.x & 63, wid = threadIdx.x >> 6;
  int inc = s;
  #pragma unroll
  for (int o = 1; o < 64; o <<= 1){ int t = __shfl_up(inc, o); if (lane >= o) inc += t; }
  __shared__ int wsum[4];
  if (lane == 63) wsum[wid] = inc;
  __syncthreads();
  int woff = 0;
  #pragma unroll
  for (int i = 0; i < 4; i++) if (i < wid) woff += wsum[i];
  int run = blockoff[b] + woff + inc - s;
  #pragma unroll
  for (int i = 0; i < 4; i++){
    int idx = base + i;
    if (idx < N){ row_start[idx] = run; cursor[idx] = run; run += v[i]; }
  }
  if (base < N && base + 4 >= N) row_start[N] = run;
}

// ---------------- W1·al / W1·ar projection vectors (128 x 4 heads) ----------------
__global__ __launch_bounds__(256) void k_prepvec(const float* __restrict__ W1,
      const float* __restrict__ al, const float* __restrict__ ar,
      float* __restrict__ W1al4, float* __restrict__ W1ar4){
  int t = blockIdx.x*256 + threadIdx.x;   // 0..1023
  if (t >= 1024) return;
  int k = t >> 3, idx = t & 7, h = idx >> 1, side = idx & 1;
  const float* v = (side ? ar : al) + h*64;
  const float* wrow = W1 + (size_t)k*256 + h*64;
  float s = 0.f;
  #pragma unroll 8
  for (int d = 0; d < 64; d++) s += wrow[d]*v[d];
  (side ? W1ar4 : W1al4)[k*4 + h] = s;
}

// ---------------- emb -> bf16 cast + el1/er1 (exact, in emb space) ----------------
__global__ __launch_bounds__(256) void k_embcast(const float2* __restrict__ emb2,
      const float4* __restrict__ W1al4, const float4* __restrict__ W1ar4,
      unsigned* __restrict__ embb, float4* __restrict__ el4, float4* __restrict__ er4,
      int N){
  int wv = threadIdx.x >> 6, lane = threadIdx.x & 63;
  int n = blockIdx.x*4 + wv;
  if (n >= N) return;
  float2 a = emb2[(size_t)n*64 + lane];
  embb[(size_t)n*64 + lane] = packbf(a.x, a.y);
  float4 wl0 = W1al4[2*lane], wl1 = W1al4[2*lane+1];
  float4 wr0 = W1ar4[2*lane], wr1 = W1ar4[2*lane+1];
  float4 pl, pr;
  pl.x = a.x*wl0.x + a.y*wl1.x; pl.y = a.x*wl0.y + a.y*wl1.y;
  pl.z = a.x*wl0.z + a.y*wl1.z; pl.w = a.x*wl0.w + a.y*wl1.w;
  pr.x = a.x*wr0.x + a.y*wr1.x; pr.y = a.x*wr0.y + a.y*wr1.y;
  pr.z = a.x*wr0.z + a.y*wr1.z; pr.w = a.x*wr0.w + a.y*wr1.w;
  #pragma unroll
  for (int o = 1; o < 64; o <<= 1){
    pl.x += __shfl_xor(pl.x, o); pl.y += __shfl_xor(pl.y, o);
    pl.z += __shfl_xor(pl.z, o); pl.w += __shfl_xor(pl.w, o);
    pr.x += __shfl_xor(pr.x, o); pr.y += __shfl_xor(pr.y, o);
    pr.z += __shfl_xor(pr.z, o); pr.w += __shfl_xor(pr.w, o);
  }
  if (lane == 0){ el4[n] = pl; er4[n] = pr; }
}

// fill + layer-1 edge weights fused
__global__ void k_fillw4(const int* __restrict__ dst, const int* __restrict__ src,
                         int* __restrict__ cursor, int* __restrict__ srcp,
                         int* __restrict__ dstp,
                         const float4* __restrict__ el4, const float4* __restrict__ er4,
                         float4* __restrict__ w4, int E){
  int i = blockIdx.x*blockDim.x + threadIdx.x;
  if (i < E){
    int d = dst[i], s = src[i];
    int p = atomicAdd(&cursor[d], 1);
    srcp[p] = s; dstp[p] = d;
    float4 l = el4[s], r = er4[d];
    float4 w;
    w.x = __expf(lrelu(l.x + r.x));
    w.y = __expf(lrelu(l.y + r.y));
    w.z = __expf(lrelu(l.z + r.z));
    w.w = __expf(lrelu(l.w + r.w));
    w4[p] = w;
  }
}

// layer-2 edge weights
__global__ void k_edgew1(const int* __restrict__ srcp, const int* __restrict__ dstp,
                         const float* __restrict__ el, const float* __restrict__ er,
                         float* __restrict__ w1, int E){
  int i = blockIdx.x*blockDim.x + threadIdx.x;
  if (i < E) w1[i] = __expf(lrelu(el[srcp[i]] + er[dstp[i]]));
}

// ---------------- layer-1 aggregation in EMB space (256 B/edge), grid-stride ----------------
// agg[n][h][0:128] = (sum_e w_e^h * emb_bf[src_e]) / S_h, stored bf16.
__global__ __launch_bounds__(256) void k_gath4e(const char* __restrict__ embb, // bf16 [N][128]
      const float4* __restrict__ w4, const int* __restrict__ row_start,
      const int* __restrict__ srcp, uint4* __restrict__ aggb, int N, int nwaves){
  int wv = threadIdx.x >> 6, lane = threadIdx.x & 63;
  int g = lane >> 4, j = lane & 15;
  const char* fb = embb + (unsigned)(j << 4);   // lane j reads 16B of the 256B row

  int n = blockIdx.x*4 + wv;
  if (n >= N) return;
  int rs = row_start[n], re = row_start[n+1];

  while (true){
    int deg = re - rs;
    int nn = n + nwaves;
    int rs_n = 0, re_n = 0;
    if (nn < N){ rs_n = row_start[nn]; re_n = row_start[nn+1]; }

    float acc[4][8];
    #pragma unroll
    for (int h = 0; h < 4; h++)
      #pragma unroll
      for (int d = 0; d < 8; d++) acc[h][d] = 0.f;
    float S0 = 0.f, S1 = 0.f, S2 = 0.f, S3 = 0.f;

    int i = 0;
    int full = deg & ~15;
    for (; i < full; i += 16){            // unguarded: 16 edges per iter
      uint4 u[4]; float4 w[4];
      #pragma unroll
      for (int k = 0; k < 4; k++){
        int e = rs + i + k*4 + g;
        int sb = srcp[e];
        w[k] = w4[e];
        u[k] = *(const uint4*)(fb + (size_t)sb*256u);
      }
      #pragma unroll
      for (int k = 0; k < 4; k++){
        float4 wk = w[k];
        S0 += wk.x; S1 += wk.y; S2 += wk.z; S3 += wk.w;
        float x[8];
        x[0]=bf_lo(u[k].x); x[1]=bf_hi(u[k].x); x[2]=bf_lo(u[k].y); x[3]=bf_hi(u[k].y);
        x[4]=bf_lo(u[k].z); x[5]=bf_hi(u[k].z); x[6]=bf_lo(u[k].w); x[7]=bf_hi(u[k].w);
        #pragma unroll
        for (int d = 0; d < 8; d++){
          acc[0][d] += x[d]*wk.x; acc[1][d] += x[d]*wk.y;
          acc[2][d] += x[d]*wk.z; acc[3][d] += x[d]*wk.w;
        }
      }
    }
    if (i < deg){                         // guarded tail (<=15 edges)
      uint4 u[4]; float4 w[4];
      #pragma unroll
      for (int k = 0; k < 4; k++){
        int e = i + k*4 + g;
        w[k] = make_float4(0.f,0.f,0.f,0.f);
        u[k] = make_uint4(0,0,0,0);
        if (e < deg){
          int sb = srcp[rs + e];
          w[k] = w4[rs + e];
          u[k] = *(const uint4*)(fb + (size_t)sb*256u);
        }
      }
      #pragma unroll
      for (int k = 0; k < 4; k++){
        float4 wk = w[k];
        S0 += wk.x; S1 += wk.y; S2 += wk.z; S3 += wk.w;
        float x[8];
        x[0]=bf_lo(u[k].x); x[1]=bf_hi(u[k].x); x[2]=bf_lo(u[k].y); x[3]=bf_hi(u[k].y);
        x[4]=bf_lo(u[k].z); x[5]=bf_hi(u[k].z); x[6]=bf_lo(u[k].w); x[7]=bf_hi(u[k].w);
        #pragma unroll
        for (int d = 0; d < 8; d++){
          acc[0][d] += x[d]*wk.x; acc[1][d] += x[d]*wk.y;
          acc[2][d] += x[d]*wk.z; acc[3][d] += x[d]*wk.w;
        }
      }
    }

    // reduce across 4 groups
    #pragma unroll
    for (int h = 0; h < 4; h++)
      #pragma unroll
      for (int d = 0; d < 8; d++){
        acc[h][d] += __shfl_xor(acc[h][d], 16);
        acc[h][d] += __shfl_xor(acc[h][d], 32);
      }
    S0 += __shfl_xor(S0, 16); S0 += __shfl_xor(S0, 32);
    S1 += __shfl_xor(S1, 16); S1 += __shfl_xor(S1, 32);
    S2 += __shfl_xor(S2, 16); S2 += __shfl_xor(S2, 32);
    S3 += __shfl_xor(S3, 16); S3 += __shfl_xor(S3, 32);

    if (g == 0){
      float Sv[4] = {S0, S1, S2, S3};
      #pragma unroll
      for (int h = 0; h < 4; h++){
        float inv = (deg > 0 && Sv[h] > 0.f) ? 1.f/Sv[h] : 0.f;
        uint4 o;
        o.x = packbf(acc[h][0]*inv, acc[h][1]*inv);
        o.y = packbf(acc[h][2]*inv, acc[h][3]*inv);
        o.z = packbf(acc[h][4]*inv, acc[h][5]*inv);
        o.w = packbf(acc[h][6]*inv, acc[h][7]*inv);
        aggb[(size_t)n*64 + h*16 + j] = o;   // [N][4][128] bf16
      }
    }

    if (nn >= N) break;
    n = nn; rs = rs_n; re = re_n;
  }
}

// ---------------- per-head MFMA GEMM: h1 = relu(agg_h @ W1_h + b1_h) ----------------
__global__ __launch_bounds__(256) void k_gemm_agg(const __hip_bfloat16* __restrict__ A, // [M][512]
      const float* __restrict__ B,      // W1 [128][256]
      const float* __restrict__ bias,   // b1 [256]
      unsigned short* __restrict__ C,   // h1b [M][256]
      int M){
  __shared__ alignas(16) __hip_bfloat16 At[64][136];
  __shared__ alignas(16) __hip_bfloat16 Bt[64][136];
  const int tid = threadIdx.x;
  const int lane = tid & 63, w = tid >> 6;
  const int mw = w >> 1, nw = w & 1;
  const int m0 = blockIdx.x * 64, by = blockIdx.y, n0 = by * 64;

  #pragma unroll
  for (int i = 0; i < 4; i++){            // A: 64 rows x 128 cols (head by)
    int q = tid + i*256;
    int row = q >> 4, c8 = q & 15;
    uint4 u = make_uint4(0,0,0,0);
    if (m0 + row < M) u = *(const uint4*)&A[(size_t)(m0+row)*512 + by*128 + c8*8];
    *(uint4*)&At[row][c8*8] = u;
  }
  #pragma unroll
  for (int i = 0; i < 8; i++){            // B: 128 x 64 transposed
    int q = tid + i*256;
    int c = q & 63, k4 = q >> 6;
    float b0 = B[(size_t)(k4*4+0)*256 + n0 + c];
    float b1 = B[(size_t)(k4*4+1)*256 + n0 + c];
    float b2 = B[(size_t)(k4*4+2)*256 + n0 + c];
    float b3 = B[(size_t)(k4*4+3)*256 + n0 + c];
    *(uint2*)&Bt[c][k4*4] = make_uint2(packbf(b0,b1), packbf(b2,b3));
  }
  __syncthreads();

  f32x4 acc[2][2];
  #pragma unroll
  for (int i = 0; i < 2; i++)
    #pragma unroll
    for (int jj = 0; jj < 2; jj++)
      #pragma unroll
      for (int r = 0; r < 4; r++) acc[i][jj][r] = 0.f;

  const int rbase = mw*32, cbase = nw*32;
  const int fr = lane & 15, fg = lane >> 4;
  #pragma unroll
  for (int ks = 0; ks < 4; ks++){
    short8v a0 = *(const short8v*)&At[rbase + fr     ][ks*32 + fg*8];
    short8v a1 = *(const short8v*)&At[rbase + 16 + fr][ks*32 + fg*8];
    short8v b0 = *(const short8v*)&Bt[cbase + fr     ][ks*32 + fg*8];
    short8v b1 = *(const short8v*)&Bt[cbase + 16 + fr][ks*32 + fg*8];
    acc[0][0] = __builtin_amdgcn_mfma_f32_16x16x32_bf16(a0, b0, acc[0][0], 0,0,0);
    acc[0][1] = __builtin_amdgcn_mfma_f32_16x16x32_bf16(a0, b1, acc[0][1], 0,0,0);
    acc[1][0] = __builtin_amdgcn_mfma_f32_16x16x32_bf16(a1, b0, acc[1][0], 0,0,0);
    acc[1][1] = __builtin_amdgcn_mfma_f32_16x16x32_bf16(a1, b1, acc[1][1], 0,0,0);
  }

  #pragma unroll
  for (int mt = 0; mt < 2; mt++){
    #pragma unroll
    for (int r = 0; r < 4; r++){
      int row = m0 + rbase + mt*16 + fg*4 + r;
      if (row < M){
        #pragma unroll
        for (int nt = 0; nt < 2; nt++){
          int col = cbase + nt*16 + fr;
          float v = acc[mt][nt][r] + bias[n0 + col];
          v = fmaxf(v, 0.f);
          C[(size_t)row*256 + n0 + col] = f2bf(v);
        }
      }
    }
  }
}

// ---------------- MFMA bf16 GEMM (layer 2), full-K LDS, fused el/er ----------------
template<int K, int H, bool ABF>
__global__ __launch_bounds__(256) void k_gemm_mfma(const void* __restrict__ Av,
      const float* __restrict__ B, int ldb,
      unsigned short* __restrict__ Cbf,
      const float* __restrict__ al, const float* __restrict__ ar,
      float* __restrict__ el, float* __restrict__ er, int M){
  constexpr int KP = K + 8;
  __shared__ alignas(16) __hip_bfloat16 At[64][KP];
  __shared__ alignas(16) __hip_bfloat16 Bt[64][KP];
  __shared__ float elp[2][64], erp[2][64];
  const int tid = threadIdx.x;
  const int lane = tid & 63, w = tid >> 6;
  const int mw = w >> 1, nw = w & 1;
  const int m0 = blockIdx.x * 64, by = blockIdx.y, n0 = by * 64;

  if constexpr (!ABF){
    const float* A = (const float*)Av;
    #pragma unroll
    for (int i = 0; i < K/16; i++){
      int q = tid + i*256;
      int row = q / (K/4), c4 = q % (K/4);
      float4 a = make_float4(0.f,0.f,0.f,0.f);
      if (m0 + row < M) a = *(const float4*)&A[(size_t)(m0+row)*K + c4*4];
      *(uint2*)&At[row][c4*4] = make_uint2(packbf(a.x,a.y), packbf(a.z,a.w));
    }
  } else {
    const __hip_bfloat16* A = (const __hip_bfloat16*)Av;
    #pragma unroll
    for (int i = 0; i < K/32; i++){
      int q = tid + i*256;
      int row = q / (K/8), c8 = q % (K/8);
      uint4 u = make_uint4(0,0,0,0);
      if (m0 + row < M) u = *(const uint4*)&A[(size_t)(m0+row)*K + c8*8];
      *(uint4*)&At[row][c8*8] = u;
    }
  }
  #pragma unroll
  for (int i = 0; i < K/16; i++){
    int q = tid + i*256;
    int c = q & 63, k4 = q >> 6;
    float b0 = B[(size_t)(k4*4+0)*ldb + n0 + c];
    float b1 = B[(size_t)(k4*4+1)*ldb + n0 + c];
    float b2 = B[(size_t)(k4*4+2)*ldb + n0 + c];
    float b3 = B[(size_t)(k4*4+3)*ldb + n0 + c];
    *(uint2*)&Bt[c][k4*4] = make_uint2(packbf(b0,b1), packbf(b2,b3));
  }
  __syncthreads();

  f32x4 acc[2][2];
  #pragma unroll
  for (int i = 0; i < 2; i++)
    #pragma unroll
    for (int j = 0; j < 2; j++)
      #pragma unroll
      for (int r = 0; r < 4; r++) acc[i][j][r] = 0.f;

  const int rbase = mw*32, cbase = nw*32;
  const int fr = lane & 15, fg = lane >> 4;
  #pragma unroll
  for (int ks = 0; ks < K/32; ks++){
    short8v a0 = *(const short8v*)&At[rbase + fr     ][ks*32 + fg*8];
    short8v a1 = *(const short8v*)&At[rbase + 16 + fr][ks*32 + fg*8];
    short8v b0 = *(const short8v*)&Bt[cbase + fr     ][ks*32 + fg*8];
    short8v b1 = *(const short8v*)&Bt[cbase + 16 + fr][ks*32 + fg*8];
    acc[0][0] = __builtin_amdgcn_mfma_f32_16x16x32_bf16(a0, b0, acc[0][0], 0,0,0);
    acc[0][1] = __builtin_amdgcn_mfma_f32_16x16x32_bf16(a0, b1, acc[0][1], 0,0,0);
    acc[1][0] = __builtin_amdgcn_mfma_f32_16x16x32_bf16(a1, b0, acc[1][0], 0,0,0);
    acc[1][1] = __builtin_amdgcn_mfma_f32_16x16x32_bf16(a1, b1, acc[1][1], 0,0,0);
  }

  float alv[2], arv[2];
  #pragma unroll
  for (int nt = 0; nt < 2; nt++){
    int col = cbase + nt*16 + fr;
    alv[nt] = al[by*64 + col];
    arv[nt] = ar[by*64 + col];
  }
  #pragma unroll
  for (int mt = 0; mt < 2; mt++){
    #pragma unroll
    for (int r = 0; r < 4; r++){
      float pl = acc[mt][0][r]*alv[0] + acc[mt][1][r]*alv[1];
      float pr = acc[mt][0][r]*arv[0] + acc[mt][1][r]*arv[1];
      #pragma unroll
      for (int o = 1; o < 16; o <<= 1){ pl += __shfl_xor(pl, o); pr += __shfl_xor(pr, o); }
      if (fr == 0){
        int rl = rbase + mt*16 + fg*4 + r;
        elp[nw][rl] = pl; erp[nw][rl] = pr;
      }
    }
  }
  const int NN = H*64;
  #pragma unroll
  for (int mt = 0; mt < 2; mt++){
    #pragma unroll
    for (int r = 0; r < 4; r++){
      int row = m0 + rbase + mt*16 + fg*4 + r;
      if (row < M){
        #pragma unroll
        for (int nt = 0; nt < 2; nt++)
          Cbf[(size_t)row*NN + n0 + cbase + nt*16 + fr] = f2bf(acc[mt][nt][r]);
      }
    }
  }
  __syncthreads();
  if (tid < 64){
    int row = m0 + tid;
    if (row < M){
      el[(size_t)row*H + by] = elp[0][tid] + elp[1][tid];
      er[(size_t)row*H + by] = erp[0][tid] + erp[1][tid];
    }
  }
}

// ---------------- pure gather-aggregate, H=1 (layer 2), grid-stride, fp32 out ----------------
__global__ __launch_bounds__(256) void k_gath1(const char* __restrict__ featb,
      const float* __restrict__ w1, const int* __restrict__ row_start,
      const int* __restrict__ srcp, const float* __restrict__ bias,
      float* __restrict__ out, int N, int nwaves){
  int wv = threadIdx.x >> 6, lane = threadIdx.x & 63;
  int g = lane >> 4, j = lane & 15;
  const char* fb = featb + (unsigned)(j << 3);

  int n = blockIdx.x*4 + wv;
  if (n >= N) return;
  int rs = row_start[n], re = row_start[n+1];

  while (true){
    int deg = re - rs;
    int nn = n + nwaves;
    int rs_n = 0, re_n = 0;
    if (nn < N){ rs_n = row_start[nn]; re_n = row_start[nn+1]; }

    float acc[4] = {0.f, 0.f, 0.f, 0.f};
    float Sacc = 0.f;

    int i = 0;
    int full = deg & ~15;
    for (; i < full; i += 16){
      float wb[4]; uint2 u[4];
      #pragma unroll
      for (int k = 0; k < 4; k++){
        int e = rs + i + k*4 + g;
        int sb = srcp[e];
        wb[k] = w1[e];
        u[k] = *(const uint2*)(fb + (size_t)sb*128u);
      }
      #pragma unroll
      for (int k = 0; k < 4; k++){
        float wk = wb[k];
        Sacc += wk;
        acc[0] += bf_lo(u[k].x)*wk; acc[1] += bf_hi(u[k].x)*wk;
        acc[2] += bf_lo(u[k].y)*wk; acc[3] += bf_hi(u[k].y)*wk;
      }
    }
    if (i < deg){
      float wb[4]; uint2 u[4];
      #pragma unroll
      for (int k = 0; k < 4; k++){
        int e = i + k*4 + g;
        wb[k] = 0.f;
        u[k] = make_uint2(0,0);
        if (e < deg){
          int sb = srcp[rs + e];
          wb[k] = w1[rs + e];
          u[k] = *(const uint2*)(fb + (size_t)sb*128u);
        }
      }
      #pragma unroll
      for (int k = 0; k < 4; k++){
        float wk = wb[k];
        Sacc += wk;
        acc[0] += bf_lo(u[k].x)*wk; acc[1] += bf_hi(u[k].x)*wk;
        acc[2] += bf_lo(u[k].y)*wk; acc[3] += bf_hi(u[k].y)*wk;
      }
    }

    #pragma unroll
    for (int k = 0; k < 4; k++){
      acc[k] += __shfl_xor(acc[k], 16);
      acc[k] += __shfl_xor(acc[k], 32);
    }
    Sacc += __shfl_xor(Sacc, 16);
    Sacc += __shfl_xor(Sacc, 32);
    if (g == 0){
      float inv = (deg > 0 && Sacc > 0.f) ? 1.f / Sacc : 0.f;
      float4 b = *(const float4*)&bias[j*4];
      float4 o;
      o.x = acc[0]*inv + b.x; o.y = acc[1]*inv + b.y;
      o.z = acc[2]*inv + b.z; o.w = acc[3]*inv + b.w;
      *(float4*)&out[(size_t)n*64 + j*4] = o;
    }

    if (nn >= N) break;
    n = nn; rs = rs_n; re = re_n;
  }
}

// ---------------- launch ----------------
extern "C" void kernel_launch(void* const* d_in, const int* in_sizes, int n_in,
                              void* d_out, int out_size, void* d_ws, size_t ws_size,
                              hipStream_t stream) {
  const float* emb = (const float*)d_in[0];
  const int*   src = (const int*)d_in[1];
  const int*   dst = (const int*)d_in[2];
  const float* W1  = (const float*)d_in[3];
  const float* al1 = (const float*)d_in[4];
  const float* ar1 = (const float*)d_in[5];
  const float* b1  = (const float*)d_in[6];
  const float* W2  = (const float*)d_in[7];
  const float* al2 = (const float*)d_in[8];
  const float* ar2 = (const float*)d_in[9];
  const float* b2  = (const float*)d_in[10];
  float* out = (float*)d_out;

  const int N = in_sizes[0] / 128;
  const int E = in_sizes[1];

  char* p = (char*)d_ws;
  auto alloc = [&](size_t bytes) -> void* {
    void* r = (void*)p; p += (bytes + 255) & ~(size_t)255; return r;
  };
  __hip_bfloat16* embb   = (__hip_bfloat16*)alloc((size_t)N*128*2);
  __hip_bfloat16* aggb   = (__hip_bfloat16*)alloc((size_t)N*512*2);
  __hip_bfloat16* h1b    = (__hip_bfloat16*)alloc((size_t)N*256*2);
  __hip_bfloat16* feat2b = (__hip_bfloat16*)alloc((size_t)N*64*2);
  float* W1al4           = (float*)alloc(128*4*4);
  float* W1ar4           = (float*)alloc(128*4*4);
  float* el1             = (float*)alloc((size_t)N*4*4);
  float* er1             = (float*)alloc((size_t)N*4*4);
  float* el2             = (float*)alloc((size_t)N*4);
  float* er2             = (float*)alloc((size_t)N*4);
  int*   deg             = (int*)alloc((size_t)N*4);
  int*   row_start       = (int*)alloc((size_t)(N+1)*4);
  int*   cursor          = (int*)alloc((size_t)N*4);
  int*   blocksum        = (int*)alloc((size_t)DIV_UP(N,1024)*4);
  int*   srcp            = (int*)alloc((size_t)E*4);
  int*   dstp            = (int*)alloc((size_t)E*4);
  float* w4              = (float*)alloc((size_t)E*16);
  float* w1              = w4;   // layer-2 weights reuse

  const int nb = DIV_UP(N, 1024);
  const int gblocks = min(DIV_UP(N, 4), 2048);
  const int nwaves  = gblocks * 4;

  hipMemsetAsync(deg, 0, (size_t)N*4, stream);
  k_count_deg<<<DIV_UP(E,256), 256, 0, stream>>>(dst, deg, E);
  k_scan1<<<nb, 256, 0, stream>>>(deg, blocksum, N);
  k_scan2<<<1, 64, 0, stream>>>(blocksum, nb);
  k_scan3<<<nb, 256, 0, stream>>>(deg, blocksum, row_start, cursor, N);

  // Layer 1 (aggregate in emb space; GEMM after aggregation)
  k_prepvec<<<4, 256, 0, stream>>>(W1, al1, ar1, W1al4, W1ar4);
  k_embcast<<<DIV_UP(N,4), 256, 0, stream>>>((const float2*)emb,
      (const float4*)W1al4, (const float4*)W1ar4,
      (unsigned*)embb, (float4*)el1, (float4*)er1, N);
  k_fillw4<<<DIV_UP(E,256), 256, 0, stream>>>(dst, src, cursor, srcp, dstp,
      (const float4*)el1, (const float4*)er1, (float4*)w4, E);
  k_gath4e<<<gblocks, 256, 0, stream>>>((const char*)embb, (const float4*)w4,
      row_start, srcp, (uint4*)aggb, N, nwaves);
  k_gemm_agg<<<dim3(DIV_UP(N,64), 4), 256, 0, stream>>>(aggb, W1, b1,
      (unsigned short*)h1b, N);

  // Layer 2
  k_gemm_mfma<256,1,true><<<dim3(DIV_UP(N,64), 1), 256, 0, stream>>>(
      h1b, W2, 64, (unsigned short*)feat2b, al2, ar2, el2, er2, N);
  k_edgew1<<<DIV_UP(E,256), 256, 0, stream>>>(srcp, dstp, el2, er2, w1, E);
  k_gath1<<<gblocks, 256, 0, stream>>>((const char*)feat2b, w1, row_start,
                                       srcp, b2, out, N, nwaves);
}

// Round 9
// 261.747 us; speedup vs baseline: 1.0085x; 1.0085x over previous
//
#include <hip/hip_runtime.h>
#include <hip/hip_bf16.h>
#include <math.h>

#define DIV_UP(a,b) (((a)+(b)-1)/(b))

typedef __attribute__((ext_vector_type(8))) short short8v;
typedef __attribute__((ext_vector_type(4))) float f32x4;

__device__ __forceinline__ float bf_lo(unsigned u){ union{unsigned x; float f;} v; v.x = u << 16; return v.f; }
__device__ __forceinline__ float bf_hi(unsigned u){ union{unsigned x; float f;} v; v.x = u & 0xffff0000u; return v.f; }
__device__ __forceinline__ unsigned short f2bf(float f){
  union{float f; unsigned u;} v; v.f = f;
  unsigned r = v.u + 0x7fff + ((v.u >> 16) & 1);   // round-nearest-even
  return (unsigned short)(r >> 16);
}
__device__ __forceinline__ unsigned packbf(float a, float b){
  return (unsigned)f2bf(a) | ((unsigned)f2bf(b) << 16);
}
__device__ __forceinline__ float lrelu(float x){ return x > 0.f ? x : 0.2f*x; }

// ---------------- CSR build ----------------
__global__ void k_count_deg(const int* __restrict__ dst, int* __restrict__ deg, int E){
  int i = blockIdx.x*blockDim.x + threadIdx.x;
  if (i < E) atomicAdd(&deg[dst[i]], 1);
}

__global__ __launch_bounds__(256) void k_scan1(const int* __restrict__ deg,
                                               int* __restrict__ blocksum, int N){
  int b = blockIdx.x;
  int base = b*1024 + threadIdx.x*4;
  int s = 0;
  if (base + 3 < N){
    int4 v = *(const int4*)&deg[base];
    s = v.x + v.y + v.z + v.w;
  } else {
    for (int i = 0; i < 4; i++){ int idx = base + i; if (idx < N) s += deg[idx]; }
  }
  #pragma unroll
  for (int o = 32; o; o >>= 1) s += __shfl_down(s, o);
  __shared__ int ws[4];
  int wid = threadIdx.x >> 6, lane = threadIdx.x & 63;
  if (lane == 0) ws[wid] = s;
  __syncthreads();
  if (threadIdx.x == 0) blocksum[b] = ws[0] + ws[1] + ws[2] + ws[3];
}

__global__ void k_scan2(int* __restrict__ blocksum, int nb){
  int lane = threadIdx.x;  // 64 threads
  int carry = 0;
  for (int base = 0; base < nb; base += 64){
    int idx = base + lane;
    int orig = (idx < nb) ? blocksum[idx] : 0;
    int v = orig;
    #pragma unroll
    for (int o = 1; o < 64; o <<= 1){ int t = __shfl_up(v, o); if (lane >= o) v += t; }
    if (idx < nb) blocksum[idx] = carry + v - orig;   // exclusive
    carry += __shfl(v, 63);
  }
}

__global__ __launch_bounds__(256) void k_scan3(const int* __restrict__ deg,
                                               const int* __restrict__ blockoff,
                                               int* __restrict__ row_start,
                                               int* __restrict__ cursor, int N){
  int b = blockIdx.x;
  int base = b*1024 + threadIdx.x*4;
  int v[4];
  #pragma unroll
  for (int i = 0; i < 4; i++){ int idx = base + i; v[i] = (idx < N) ? deg[idx] : 0; }
  int s = v[0] + v[1] + v[2] + v[3];
  int lane = threadIdx.x & 63, wid = threadIdx.x >> 6;
  int inc = s;
  #pragma unroll
  for (int o = 1; o < 64; o <<= 1){ int t = __shfl_up(inc, o); if (lane >= o) inc += t; }
  __shared__ int wsum[4];
  if (lane == 63) wsum[wid] = inc;
  __syncthreads();
  int woff = 0;
  #pragma unroll
  for (int i = 0; i < 4; i++) if (i < wid) woff += wsum[i];
  int run = blockoff[b] + woff + inc - s;
  #pragma unroll
  for (int i = 0; i < 4; i++){
    int idx = base + i;
    if (idx < N){ row_start[idx] = run; cursor[idx] = run; run += v[i]; }
  }
  if (base < N && base + 4 >= N) row_start[N] = run;
}

// plain CSR fill: src node id per slot
__global__ void k_fill(const int* __restrict__ dst, const int* __restrict__ src,
                       int* __restrict__ cursor, int* __restrict__ srcp, int E){
  int i = blockIdx.x*blockDim.x + threadIdx.x;
  if (i < E){ int p = atomicAdd(&cursor[dst[i]], 1); srcp[p] = src[i]; }
}

// ---------------- GEMM1: 64 rows x 256 cols (all 4 heads) per block ----------------
// A emb fp32 [M][128]; B W1 fp32 [128][256]; out bf16 feat1 + el/er per head.
__global__ __launch_bounds__(512) void k_gemm1h4(const float* __restrict__ A,
      const float* __restrict__ B,
      unsigned short* __restrict__ Cbf,
      const float* __restrict__ al, const float* __restrict__ ar,
      float* __restrict__ el, float* __restrict__ er, int M){
  __shared__ alignas(16) __hip_bfloat16 At[64][136];
  __shared__ alignas(16) __hip_bfloat16 Bt[256][136];
  __shared__ float elp[8][64], erp[8][64];
  const int tid = threadIdx.x;
  const int lane = tid & 63, w = tid >> 6;     // 8 waves
  const int m0 = blockIdx.x * 64;
  const int fr = lane & 15, fg = lane >> 4;
  const int cbase = w * 32;

  #pragma unroll
  for (int i = 0; i < 4; i++){                 // A: 64 x 128 fp32 -> bf16
    int q = tid + i*512;
    int row = q >> 5, c4 = q & 31;
    float4 a = make_float4(0.f,0.f,0.f,0.f);
    if (m0 + row < M) a = *(const float4*)&A[(size_t)(m0+row)*128 + c4*4];
    *(uint2*)&At[row][c4*4] = make_uint2(packbf(a.x,a.y), packbf(a.z,a.w));
  }
  #pragma unroll
  for (int i = 0; i < 16; i++){                // B: 128 x 256 transposed -> Bt[col][k]
    int q = tid + i*512;
    int col = q & 255, k4 = q >> 8;
    float b0 = B[(size_t)(k4*4+0)*256 + col];
    float b1 = B[(size_t)(k4*4+1)*256 + col];
    float b2 = B[(size_t)(k4*4+2)*256 + col];
    float b3 = B[(size_t)(k4*4+3)*256 + col];
    *(uint2*)&Bt[col][k4*4] = make_uint2(packbf(b0,b1), packbf(b2,b3));
  }
  __syncthreads();

  f32x4 acc[4][2];
  #pragma unroll
  for (int mt = 0; mt < 4; mt++)
    #pragma unroll
    for (int nt = 0; nt < 2; nt++)
      #pragma unroll
      for (int r = 0; r < 4; r++) acc[mt][nt][r] = 0.f;

  #pragma unroll
  for (int ks = 0; ks < 4; ks++){
    short8v a0 = *(const short8v*)&At[ 0 + fr][ks*32 + fg*8];
    short8v a1 = *(const short8v*)&At[16 + fr][ks*32 + fg*8];
    short8v a2 = *(const short8v*)&At[32 + fr][ks*32 + fg*8];
    short8v a3 = *(const short8v*)&At[48 + fr][ks*32 + fg*8];
    short8v b0 = *(const short8v*)&Bt[cbase      + fr][ks*32 + fg*8];
    short8v b1 = *(const short8v*)&Bt[cbase + 16 + fr][ks*32 + fg*8];
    acc[0][0] = __builtin_amdgcn_mfma_f32_16x16x32_bf16(a0, b0, acc[0][0], 0,0,0);
    acc[0][1] = __builtin_amdgcn_mfma_f32_16x16x32_bf16(a0, b1, acc[0][1], 0,0,0);
    acc[1][0] = __builtin_amdgcn_mfma_f32_16x16x32_bf16(a1, b0, acc[1][0], 0,0,0);
    acc[1][1] = __builtin_amdgcn_mfma_f32_16x16x32_bf16(a1, b1, acc[1][1], 0,0,0);
    acc[2][0] = __builtin_amdgcn_mfma_f32_16x16x32_bf16(a2, b0, acc[2][0], 0,0,0);
    acc[2][1] = __builtin_amdgcn_mfma_f32_16x16x32_bf16(a2, b1, acc[2][1], 0,0,0);
    acc[3][0] = __builtin_amdgcn_mfma_f32_16x16x32_bf16(a3, b0, acc[3][0], 0,0,0);
    acc[3][1] = __builtin_amdgcn_mfma_f32_16x16x32_bf16(a3, b1, acc[3][1], 0,0,0);
  }

  float alv[2], arv[2];
  #pragma unroll
  for (int nt = 0; nt < 2; nt++){
    int col = cbase + nt*16 + fr;
    alv[nt] = al[col]; arv[nt] = ar[col];
  }
  #pragma unroll
  for (int mt = 0; mt < 4; mt++){
    #pragma unroll
    for (int r = 0; r < 4; r++){
      float pl = acc[mt][0][r]*alv[0] + acc[mt][1][r]*alv[1];
      float pr = acc[mt][0][r]*arv[0] + acc[mt][1][r]*arv[1];
      #pragma unroll
      for (int o = 1; o < 16; o <<= 1){ pl += __shfl_xor(pl, o); pr += __shfl_xor(pr, o); }
      if (fr == 0){
        int rl = mt*16 + fg*4 + r;
        elp[w][rl] = pl; erp[w][rl] = pr;
      }
    }
  }
  #pragma unroll
  for (int mt = 0; mt < 4; mt++){
    #pragma unroll
    for (int r = 0; r < 4; r++){
      int row = m0 + mt*16 + fg*4 + r;
      if (row < M){
        #pragma unroll
        for (int nt = 0; nt < 2; nt++)
          Cbf[(size_t)row*256 + cbase + nt*16 + fr] = f2bf(acc[mt][nt][r]);
      }
    }
  }
  __syncthreads();
  if (tid < 256){
    int row = tid & 63, h = tid >> 6;
    if (m0 + row < M){
      el[(size_t)(m0+row)*4 + h] = elp[2*h][row] + elp[2*h+1][row];
      er[(size_t)(m0+row)*4 + h] = erp[2*h][row] + erp[2*h+1][row];
    }
  }
}

// ---------------- GEMM2 (layer 2), 64x64, full-K LDS, fused el/er ----------------
template<int K, int H, bool ABF>
__global__ __launch_bounds__(256) void k_gemm_mfma(const void* __restrict__ Av,
      const float* __restrict__ B, int ldb,
      unsigned short* __restrict__ Cbf,
      const float* __restrict__ al, const float* __restrict__ ar,
      float* __restrict__ el, float* __restrict__ er, int M){
  constexpr int KP = K + 8;
  __shared__ alignas(16) __hip_bfloat16 At[64][KP];
  __shared__ alignas(16) __hip_bfloat16 Bt[64][KP];
  __shared__ float elp[2][64], erp[2][64];
  const int tid = threadIdx.x;
  const int lane = tid & 63, w = tid >> 6;
  const int mw = w >> 1, nw = w & 1;
  const int m0 = blockIdx.x * 64, by = blockIdx.y, n0 = by * 64;

  if constexpr (!ABF){
    const float* A = (const float*)Av;
    #pragma unroll
    for (int i = 0; i < K/16; i++){
      int q = tid + i*256;
      int row = q / (K/4), c4 = q % (K/4);
      float4 a = make_float4(0.f,0.f,0.f,0.f);
      if (m0 + row < M) a = *(const float4*)&A[(size_t)(m0+row)*K + c4*4];
      *(uint2*)&At[row][c4*4] = make_uint2(packbf(a.x,a.y), packbf(a.z,a.w));
    }
  } else {
    const __hip_bfloat16* A = (const __hip_bfloat16*)Av;
    #pragma unroll
    for (int i = 0; i < K/32; i++){
      int q = tid + i*256;
      int row = q / (K/8), c8 = q % (K/8);
      uint4 u = make_uint4(0,0,0,0);
      if (m0 + row < M) u = *(const uint4*)&A[(size_t)(m0+row)*K + c8*8];
      *(uint4*)&At[row][c8*8] = u;
    }
  }
  #pragma unroll
  for (int i = 0; i < K/16; i++){
    int q = tid + i*256;
    int c = q & 63, k4 = q >> 6;
    float b0 = B[(size_t)(k4*4+0)*ldb + n0 + c];
    float b1 = B[(size_t)(k4*4+1)*ldb + n0 + c];
    float b2 = B[(size_t)(k4*4+2)*ldb + n0 + c];
    float b3 = B[(size_t)(k4*4+3)*ldb + n0 + c];
    *(uint2*)&Bt[c][k4*4] = make_uint2(packbf(b0,b1), packbf(b2,b3));
  }
  __syncthreads();

  f32x4 acc[2][2];
  #pragma unroll
  for (int i = 0; i < 2; i++)
    #pragma unroll
    for (int j = 0; j < 2; j++)
      #pragma unroll
      for (int r = 0; r < 4; r++) acc[i][j][r] = 0.f;

  const int rbase = mw*32, cbase = nw*32;
  const int fr = lane & 15, fg = lane >> 4;
  #pragma unroll
  for (int ks = 0; ks < K/32; ks++){
    short8v a0 = *(const short8v*)&At[rbase + fr     ][ks*32 + fg*8];
    short8v a1 = *(const short8v*)&At[rbase + 16 + fr][ks*32 + fg*8];
    short8v b0 = *(const short8v*)&Bt[cbase + fr     ][ks*32 + fg*8];
    short8v b1 = *(const short8v*)&Bt[cbase + 16 + fr][ks*32 + fg*8];
    acc[0][0] = __builtin_amdgcn_mfma_f32_16x16x32_bf16(a0, b0, acc[0][0], 0,0,0);
    acc[0][1] = __builtin_amdgcn_mfma_f32_16x16x32_bf16(a0, b1, acc[0][1], 0,0,0);
    acc[1][0] = __builtin_amdgcn_mfma_f32_16x16x32_bf16(a1, b0, acc[1][0], 0,0,0);
    acc[1][1] = __builtin_amdgcn_mfma_f32_16x16x32_bf16(a1, b1, acc[1][1], 0,0,0);
  }

  float alv[2], arv[2];
  #pragma unroll
  for (int nt = 0; nt < 2; nt++){
    int col = cbase + nt*16 + fr;
    alv[nt] = al[by*64 + col];
    arv[nt] = ar[by*64 + col];
  }
  #pragma unroll
  for (int mt = 0; mt < 2; mt++){
    #pragma unroll
    for (int r = 0; r < 4; r++){
      float pl = acc[mt][0][r]*alv[0] + acc[mt][1][r]*alv[1];
      float pr = acc[mt][0][r]*arv[0] + acc[mt][1][r]*arv[1];
      #pragma unroll
      for (int o = 1; o < 16; o <<= 1){ pl += __shfl_xor(pl, o); pr += __shfl_xor(pr, o); }
      if (fr == 0){
        int rl = rbase + mt*16 + fg*4 + r;
        elp[nw][rl] = pl; erp[nw][rl] = pr;
      }
    }
  }
  const int NN = H*64;
  #pragma unroll
  for (int mt = 0; mt < 2; mt++){
    #pragma unroll
    for (int r = 0; r < 4; r++){
      int row = m0 + rbase + mt*16 + fg*4 + r;
      if (row < M){
        #pragma unroll
        for (int nt = 0; nt < 2; nt++)
          Cbf[(size_t)row*NN + n0 + cbase + nt*16 + fr] = f2bf(acc[mt][nt][r]);
      }
    }
  }
  __syncthreads();
  if (tid < 64){
    int row = m0 + tid;
    if (row < M){
      el[(size_t)row*H + by] = elp[0][tid] + elp[1][tid];
      er[(size_t)row*H + by] = erp[0][tid] + erp[1][tid];
    }
  }
}

// ---------------- gather-aggregate + inline weights, H=4 (layer 1) ----------------
__global__ __launch_bounds__(256) void k_gath4w(const char* __restrict__ featb,
      const float4* __restrict__ el4, const float4* __restrict__ er4,
      const int* __restrict__ row_start, const int* __restrict__ srcp,
      const float* __restrict__ bias, __hip_bfloat16* __restrict__ outb,
      int N, int nwaves){
  int wv = threadIdx.x >> 6, lane = threadIdx.x & 63;
  int g = lane >> 4, j = lane & 15, h = j >> 2;
  const char* fb = featb + (unsigned)(j << 5);

  int n = blockIdx.x*4 + wv;
  if (n >= N) return;
  int rs = row_start[n], re = row_start[n+1];

  while (true){
    int deg = re - rs;
    int nn = n + nwaves;
    int rs_n = 0, re_n = 0;
    if (nn < N){ rs_n = row_start[nn]; re_n = row_start[nn+1]; }

    float4 ern = er4[n];
    float ernh = (h==0) ? ern.x : (h==1) ? ern.y : (h==2) ? ern.z : ern.w;

    float acc[16];
    #pragma unroll
    for (int k = 0; k < 16; k++) acc[k] = 0.f;
    float Sacc = 0.f;

    int i = 0;
    int full = deg & ~15;
    for (; i < full; i += 16){
      float wk[4]; uint4 u0[4], u1[4];
      #pragma unroll
      for (int k = 0; k < 4; k++){
        int e = rs + i + k*4 + g;
        int sb = srcp[e];
        float4 elv = el4[sb];
        float xh = (h==0) ? elv.x : (h==1) ? elv.y : (h==2) ? elv.z : elv.w;
        xh += ernh; xh = xh > 0.f ? xh : 0.2f*xh;
        wk[k] = __expf(xh);
        const char* p = fb + (size_t)sb*512u;
        u0[k] = *(const uint4*)p;
        u1[k] = *(const uint4*)(p + 16);
      }
      #pragma unroll
      for (int k = 0; k < 4; k++){
        float w = wk[k];
        Sacc += w;
        acc[0]  += bf_lo(u0[k].x)*w; acc[1]  += bf_hi(u0[k].x)*w;
        acc[2]  += bf_lo(u0[k].y)*w; acc[3]  += bf_hi(u0[k].y)*w;
        acc[4]  += bf_lo(u0[k].z)*w; acc[5]  += bf_hi(u0[k].z)*w;
        acc[6]  += bf_lo(u0[k].w)*w; acc[7]  += bf_hi(u0[k].w)*w;
        acc[8]  += bf_lo(u1[k].x)*w; acc[9]  += bf_hi(u1[k].x)*w;
        acc[10] += bf_lo(u1[k].y)*w; acc[11] += bf_hi(u1[k].y)*w;
        acc[12] += bf_lo(u1[k].z)*w; acc[13] += bf_hi(u1[k].z)*w;
        acc[14] += bf_lo(u1[k].w)*w; acc[15] += bf_hi(u1[k].w)*w;
      }
    }
    if (i < deg){
      float wk[4]; uint4 u0[4], u1[4];
      #pragma unroll
      for (int k = 0; k < 4; k++){
        int e = i + k*4 + g;
        wk[k] = 0.f;
        u0[k] = make_uint4(0,0,0,0); u1[k] = make_uint4(0,0,0,0);
        if (e < deg){
          int sb = srcp[rs + e];
          float4 elv = el4[sb];
          float xh = (h==0) ? elv.x : (h==1) ? elv.y : (h==2) ? elv.z : elv.w;
          xh += ernh; xh = xh > 0.f ? xh : 0.2f*xh;
          wk[k] = __expf(xh);
          const char* p = fb + (size_t)sb*512u;
          u0[k] = *(const uint4*)p;
          u1[k] = *(const uint4*)(p + 16);
        }
      }
      #pragma unroll
      for (int k = 0; k < 4; k++){
        float w = wk[k];
        Sacc += w;
        acc[0]  += bf_lo(u0[k].x)*w; acc[1]  += bf_hi(u0[k].x)*w;
        acc[2]  += bf_lo(u0[k].y)*w; acc[3]  += bf_hi(u0[k].y)*w;
        acc[4]  += bf_lo(u0[k].z)*w; acc[5]  += bf_hi(u0[k].z)*w;
        acc[6]  += bf_lo(u0[k].w)*w; acc[7]  += bf_hi(u0[k].w)*w;
        acc[8]  += bf_lo(u1[k].x)*w; acc[9]  += bf_hi(u1[k].x)*w;
        acc[10] += bf_lo(u1[k].y)*w; acc[11] += bf_hi(u1[k].y)*w;
        acc[12] += bf_lo(u1[k].z)*w; acc[13] += bf_hi(u1[k].z)*w;
        acc[14] += bf_lo(u1[k].w)*w; acc[15] += bf_hi(u1[k].w)*w;
      }
    }

    #pragma unroll
    for (int k = 0; k < 16; k++){
      acc[k] += __shfl_xor(acc[k], 16);
      acc[k] += __shfl_xor(acc[k], 32);
    }
    Sacc += __shfl_xor(Sacc, 16);
    Sacc += __shfl_xor(Sacc, 32);
    if (g == 0){
      float inv = (deg > 0 && Sacc > 0.f) ? 1.f / Sacc : 0.f;
      float4 b0 = *(const float4*)&bias[j*16 + 0];
      float4 b1 = *(const float4*)&bias[j*16 + 4];
      float4 b2 = *(const float4*)&bias[j*16 + 8];
      float4 b3 = *(const float4*)&bias[j*16 + 12];
      float v[16];
      v[0]=acc[0]*inv+b0.x;  v[1]=acc[1]*inv+b0.y;  v[2]=acc[2]*inv+b0.z;  v[3]=acc[3]*inv+b0.w;
      v[4]=acc[4]*inv+b1.x;  v[5]=acc[5]*inv+b1.y;  v[6]=acc[6]*inv+b1.z;  v[7]=acc[7]*inv+b1.w;
      v[8]=acc[8]*inv+b2.x;  v[9]=acc[9]*inv+b2.y;  v[10]=acc[10]*inv+b2.z; v[11]=acc[11]*inv+b2.w;
      v[12]=acc[12]*inv+b3.x; v[13]=acc[13]*inv+b3.y; v[14]=acc[14]*inv+b3.z; v[15]=acc[15]*inv+b3.w;
      #pragma unroll
      for (int k = 0; k < 16; k++) v[k] = fmaxf(v[k], 0.f);   // relu (layer 1)
      uint4 o0, o1;
      o0.x = packbf(v[0], v[1]);   o0.y = packbf(v[2], v[3]);
      o0.z = packbf(v[4], v[5]);   o0.w = packbf(v[6], v[7]);
      o1.x = packbf(v[8], v[9]);   o1.y = packbf(v[10], v[11]);
      o1.z = packbf(v[12], v[13]); o1.w = packbf(v[14], v[15]);
      uint4* op = (uint4*)outb + (size_t)n*32 + (j << 1);
      op[0] = o0; op[1] = o1;
    }

    if (nn >= N) break;
    n = nn; rs = rs_n; re = re_n;
  }
}

// ---------------- gather-aggregate + inline weights, H=1 (layer 2), fp32 out ----------------
__global__ __launch_bounds__(256) void k_gath1w(const char* __restrict__ featb,
      const float* __restrict__ el, const float* __restrict__ er,
      const int* __restrict__ row_start, const int* __restrict__ srcp,
      const float* __restrict__ bias, float* __restrict__ out, int N, int nwaves){
  int wv = threadIdx.x >> 6, lane = threadIdx.x & 63;
  int g = lane >> 4, j = lane & 15;
  const char* fb = featb + (unsigned)(j << 3);

  int n = blockIdx.x*4 + wv;
  if (n >= N) return;
  int rs = row_start[n], re = row_start[n+1];

  while (true){
    int deg = re - rs;
    int nn = n + nwaves;
    int rs_n = 0, re_n = 0;
    if (nn < N){ rs_n = row_start[nn]; re_n = row_start[nn+1]; }

    float ern = er[n];
    float acc[4] = {0.f, 0.f, 0.f, 0.f};
    float Sacc = 0.f;

    int i = 0;
    int full = deg & ~15;
    for (; i < full; i += 16){
      float wk[4]; uint2 u[4];
      #pragma unroll
      for (int k = 0; k < 4; k++){
        int e = rs + i + k*4 + g;
        int sb = srcp[e];
        float x = el[sb] + ern;
        x = x > 0.f ? x : 0.2f*x;
        wk[k] = __expf(x);
        u[k] = *(const uint2*)(fb + (size_t)sb*128u);
      }
      #pragma unroll
      for (int k = 0; k < 4; k++){
        float w = wk[k];
        Sacc += w;
        acc[0] += bf_lo(u[k].x)*w; acc[1] += bf_hi(u[k].x)*w;
        acc[2] += bf_lo(u[k].y)*w; acc[3] += bf_hi(u[k].y)*w;
      }
    }
    if (i < deg){
      float wk[4]; uint2 u[4];
      #pragma unroll
      for (int k = 0; k < 4; k++){
        int e = i + k*4 + g;
        wk[k] = 0.f;
        u[k] = make_uint2(0,0);
        if (e < deg){
          int sb = srcp[rs + e];
          float x = el[sb] + ern;
          x = x > 0.f ? x : 0.2f*x;
          wk[k] = __expf(x);
          u[k] = *(const uint2*)(fb + (size_t)sb*128u);
        }
      }
      #pragma unroll
      for (int k = 0; k < 4; k++){
        float w = wk[k];
        Sacc += w;
        acc[0] += bf_lo(u[k].x)*w; acc[1] += bf_hi(u[k].x)*w;
        acc[2] += bf_lo(u[k].y)*w; acc[3] += bf_hi(u[k].y)*w;
      }
    }

    #pragma unroll
    for (int k = 0; k < 4; k++){
      acc[k] += __shfl_xor(acc[k], 16);
      acc[k] += __shfl_xor(acc[k], 32);
    }
    Sacc += __shfl_xor(Sacc, 16);
    Sacc += __shfl_xor(Sacc, 32);
    if (g == 0){
      float inv = (deg > 0 && Sacc > 0.f) ? 1.f / Sacc : 0.f;
      float4 b = *(const float4*)&bias[j*4];
      float4 o;
      o.x = acc[0]*inv + b.x; o.y = acc[1]*inv + b.y;
      o.z = acc[2]*inv + b.z; o.w = acc[3]*inv + b.w;
      *(float4*)&out[(size_t)n*64 + j*4] = o;
    }

    if (nn >= N) break;
    n = nn; rs = rs_n; re = re_n;
  }
}

// ---------------- launch ----------------
extern "C" void kernel_launch(void* const* d_in, const int* in_sizes, int n_in,
                              void* d_out, int out_size, void* d_ws, size_t ws_size,
                              hipStream_t stream) {
  const float* emb = (const float*)d_in[0];
  const int*   src = (const int*)d_in[1];
  const int*   dst = (const int*)d_in[2];
  const float* W1  = (const float*)d_in[3];
  const float* al1 = (const float*)d_in[4];
  const float* ar1 = (const float*)d_in[5];
  const float* b1  = (const float*)d_in[6];
  const float* W2  = (const float*)d_in[7];
  const float* al2 = (const float*)d_in[8];
  const float* ar2 = (const float*)d_in[9];
  const float* b2  = (const float*)d_in[10];
  float* out = (float*)d_out;

  const int N = in_sizes[0] / 128;
  const int E = in_sizes[1];

  char* p = (char*)d_ws;
  auto alloc = [&](size_t bytes) -> void* {
    void* r = (void*)p; p += (bytes + 255) & ~(size_t)255; return r;
  };
  __hip_bfloat16* feat1b = (__hip_bfloat16*)alloc((size_t)N*256*2);
  __hip_bfloat16* h1b    = (__hip_bfloat16*)alloc((size_t)N*256*2);
  __hip_bfloat16* feat2b = (__hip_bfloat16*)alloc((size_t)N*64*2);
  float* el1             = (float*)alloc((size_t)N*4*4);
  float* er1             = (float*)alloc((size_t)N*4*4);
  float* el2             = (float*)alloc((size_t)N*4);
  float* er2             = (float*)alloc((size_t)N*4);
  int*   deg             = (int*)alloc((size_t)N*4);
  int*   row_start       = (int*)alloc((size_t)(N+1)*4);
  int*   cursor          = (int*)alloc((size_t)N*4);
  int*   blocksum        = (int*)alloc((size_t)DIV_UP(N,1024)*4);
  int*   srcp            = (int*)alloc((size_t)E*4);

  const int nb = DIV_UP(N, 1024);
  const int gblocks = min(DIV_UP(N, 4), 2048);
  const int nwaves  = gblocks * 4;

  hipMemsetAsync(deg, 0, (size_t)N*4, stream);
  k_count_deg<<<DIV_UP(E,256), 256, 0, stream>>>(dst, deg, E);
  k_scan1<<<nb, 256, 0, stream>>>(deg, blocksum, N);
  k_scan2<<<1, 64, 0, stream>>>(blocksum, nb);
  k_scan3<<<nb, 256, 0, stream>>>(deg, blocksum, row_start, cursor, N);
  k_fill<<<DIV_UP(E,256), 256, 0, stream>>>(dst, src, cursor, srcp, E);

  // Layer 1
  k_gemm1h4<<<DIV_UP(N,64), 512, 0, stream>>>(emb, W1, (unsigned short*)feat1b,
                                              al1, ar1, el1, er1, N);
  k_gath4w<<<gblocks, 256, 0, stream>>>((const char*)feat1b, (const float4*)el1,
      (const float4*)er1, row_start, srcp, b1, h1b, N, nwaves);
  // Layer 2
  k_gemm_mfma<256,1,true><<<dim3(DIV_UP(N,64), 1), 256, 0, stream>>>(
      h1b, W2, 64, (unsigned short*)feat2b, al2, ar2, el2, er2, N);
  k_gath1w<<<gblocks, 256, 0, stream>>>((const char*)feat2b, el2, er2,
      row_start, srcp, b2, out, N, nwaves);
}

// Round 10
// 235.441 us; speedup vs baseline: 1.1212x; 1.1117x over previous
//
#include <hip/hip_runtime.h>
#include <hip/hip_bf16.h>
#include <math.h>

#define DIV_UP(a,b) (((a)+(b)-1)/(b))

typedef __attribute__((ext_vector_type(8))) short short8v;
typedef __attribute__((ext_vector_type(4))) float f32x4;

__device__ __forceinline__ float bf_lo(unsigned u){ union{unsigned x; float f;} v; v.x = u << 16; return v.f; }
__device__ __forceinline__ float bf_hi(unsigned u){ union{unsigned x; float f;} v; v.x = u & 0xffff0000u; return v.f; }
__device__ __forceinline__ unsigned short f2bf(float f){
  union{float f; unsigned u;} v; v.f = f;
  unsigned r = v.u + 0x7fff + ((v.u >> 16) & 1);   // round-nearest-even
  return (unsigned short)(r >> 16);
}
__device__ __forceinline__ unsigned packbf(float a, float b){
  return (unsigned)f2bf(a) | ((unsigned)f2bf(b) << 16);
}
__device__ __forceinline__ float lrelu(float x){ return x > 0.f ? x : 0.2f*x; }

// ---------------- CSR build ----------------
__global__ void k_count_deg(const int* __restrict__ dst, int* __restrict__ deg, int E){
  int i = blockIdx.x*blockDim.x + threadIdx.x;
  if (i < E) atomicAdd(&deg[dst[i]], 1);
}

__global__ __launch_bounds__(256) void k_scan1(const int* __restrict__ deg,
                                               int* __restrict__ blocksum, int N){
  int b = blockIdx.x;
  int base = b*1024 + threadIdx.x*4;
  int s = 0;
  if (base + 3 < N){
    int4 v = *(const int4*)&deg[base];
    s = v.x + v.y + v.z + v.w;
  } else {
    for (int i = 0; i < 4; i++){ int idx = base + i; if (idx < N) s += deg[idx]; }
  }
  #pragma unroll
  for (int o = 32; o; o >>= 1) s += __shfl_down(s, o);
  __shared__ int ws[4];
  int wid = threadIdx.x >> 6, lane = threadIdx.x & 63;
  if (lane == 0) ws[wid] = s;
  __syncthreads();
  if (threadIdx.x == 0) blocksum[b] = ws[0] + ws[1] + ws[2] + ws[3];
}

__global__ void k_scan2(int* __restrict__ blocksum, int nb){
  int lane = threadIdx.x;  // 64 threads
  int carry = 0;
  for (int base = 0; base < nb; base += 64){
    int idx = base + lane;
    int orig = (idx < nb) ? blocksum[idx] : 0;
    int v = orig;
    #pragma unroll
    for (int o = 1; o < 64; o <<= 1){ int t = __shfl_up(v, o); if (lane >= o) v += t; }
    if (idx < nb) blocksum[idx] = carry + v - orig;   // exclusive
    carry += __shfl(v, 63);
  }
}

__global__ __launch_bounds__(256) void k_scan3(const int* __restrict__ deg,
                                               const int* __restrict__ blockoff,
                                               int* __restrict__ row_start,
                                               int* __restrict__ cursor, int N){
  int b = blockIdx.x;
  int base = b*1024 + threadIdx.x*4;
  int v[4];
  #pragma unroll
  for (int i = 0; i < 4; i++){ int idx = base + i; v[i] = (idx < N) ? deg[idx] : 0; }
  int s = v[0] + v[1] + v[2] + v[3];
  int lane = threadIdx.x & 63, wid = threadIdx.x >> 6;
  int inc = s;
  #pragma unroll
  for (int o = 1; o < 64; o <<= 1){ int t = __shfl_up(inc, o); if (lane >= o) inc += t; }
  __shared__ int wsum[4];
  if (lane == 63) wsum[wid] = inc;
  __syncthreads();
  int woff = 0;
  #pragma unroll
  for (int i = 0; i < 4; i++) if (i < wid) woff += wsum[i];
  int run = blockoff[b] + woff + inc - s;
  #pragma unroll
  for (int i = 0; i < 4; i++){
    int idx = base + i;
    if (idx < N){ row_start[idx] = run; cursor[idx] = run; run += v[i]; }
  }
  if (base < N && base + 4 >= N) row_start[N] = run;
}

// fill + layer-1 edge weights fused: one pass over original edges.
__global__ void k_fillw4(const int* __restrict__ dst, const int* __restrict__ src,
                         int* __restrict__ cursor, int* __restrict__ srcp,
                         int* __restrict__ dstp,
                         const float4* __restrict__ el4, const float4* __restrict__ er4,
                         float4* __restrict__ w4, int E){
  int i = blockIdx.x*blockDim.x + threadIdx.x;
  if (i < E){
    int d = dst[i], s = src[i];
    int p = atomicAdd(&cursor[d], 1);
    srcp[p] = s; dstp[p] = d;
    float4 l = el4[s], r = er4[d];
    float4 w;
    w.x = __expf(lrelu(l.x + r.x));
    w.y = __expf(lrelu(l.y + r.y));
    w.z = __expf(lrelu(l.z + r.z));
    w.w = __expf(lrelu(l.w + r.w));
    w4[p] = w;
  }
}

// layer-2 edge weights
__global__ void k_edgew1(const int* __restrict__ srcp, const int* __restrict__ dstp,
                         const float* __restrict__ el, const float* __restrict__ er,
                         float* __restrict__ w1, int E){
  int i = blockIdx.x*blockDim.x + threadIdx.x;
  if (i < E) w1[i] = __expf(lrelu(el[srcp[i]] + er[dstp[i]]));
}

// ---------------- MFMA bf16 GEMM, 64x64 tile, full-K LDS, fused el/er ----------------
template<int K, int H, bool ABF>
__global__ __launch_bounds__(256) void k_gemm_mfma(const void* __restrict__ Av,
      const float* __restrict__ B, int ldb,
      unsigned short* __restrict__ Cbf,
      const float* __restrict__ al, const float* __restrict__ ar,
      float* __restrict__ el, float* __restrict__ er, int M){
  constexpr int KP = K + 8;
  __shared__ alignas(16) __hip_bfloat16 At[64][KP];
  __shared__ alignas(16) __hip_bfloat16 Bt[64][KP];
  __shared__ float elp[2][64], erp[2][64];
  const int tid = threadIdx.x;
  const int lane = tid & 63, w = tid >> 6;
  const int mw = w >> 1, nw = w & 1;
  const int m0 = blockIdx.x * 64, by = blockIdx.y, n0 = by * 64;

  if constexpr (!ABF){
    const float* A = (const float*)Av;
    #pragma unroll
    for (int i = 0; i < K/16; i++){
      int q = tid + i*256;
      int row = q / (K/4), c4 = q % (K/4);
      float4 a = make_float4(0.f,0.f,0.f,0.f);
      if (m0 + row < M) a = *(const float4*)&A[(size_t)(m0+row)*K + c4*4];
      *(uint2*)&At[row][c4*4] = make_uint2(packbf(a.x,a.y), packbf(a.z,a.w));
    }
  } else {
    const __hip_bfloat16* A = (const __hip_bfloat16*)Av;
    #pragma unroll
    for (int i = 0; i < K/32; i++){
      int q = tid + i*256;
      int row = q / (K/8), c8 = q % (K/8);
      uint4 u = make_uint4(0,0,0,0);
      if (m0 + row < M) u = *(const uint4*)&A[(size_t)(m0+row)*K + c8*8];
      *(uint4*)&At[row][c8*8] = u;
    }
  }
  #pragma unroll
  for (int i = 0; i < K/16; i++){
    int q = tid + i*256;
    int c = q & 63, k4 = q >> 6;
    float b0 = B[(size_t)(k4*4+0)*ldb + n0 + c];
    float b1 = B[(size_t)(k4*4+1)*ldb + n0 + c];
    float b2 = B[(size_t)(k4*4+2)*ldb + n0 + c];
    float b3 = B[(size_t)(k4*4+3)*ldb + n0 + c];
    *(uint2*)&Bt[c][k4*4] = make_uint2(packbf(b0,b1), packbf(b2,b3));
  }
  __syncthreads();

  f32x4 acc[2][2];
  #pragma unroll
  for (int i = 0; i < 2; i++)
    #pragma unroll
    for (int j = 0; j < 2; j++)
      #pragma unroll
      for (int r = 0; r < 4; r++) acc[i][j][r] = 0.f;

  const int rbase = mw*32, cbase = nw*32;
  const int fr = lane & 15, fg = lane >> 4;
  #pragma unroll
  for (int ks = 0; ks < K/32; ks++){
    short8v a0 = *(const short8v*)&At[rbase + fr     ][ks*32 + fg*8];
    short8v a1 = *(const short8v*)&At[rbase + 16 + fr][ks*32 + fg*8];
    short8v b0 = *(const short8v*)&Bt[cbase + fr     ][ks*32 + fg*8];
    short8v b1 = *(const short8v*)&Bt[cbase + 16 + fr][ks*32 + fg*8];
    acc[0][0] = __builtin_amdgcn_mfma_f32_16x16x32_bf16(a0, b0, acc[0][0], 0,0,0);
    acc[0][1] = __builtin_amdgcn_mfma_f32_16x16x32_bf16(a0, b1, acc[0][1], 0,0,0);
    acc[1][0] = __builtin_amdgcn_mfma_f32_16x16x32_bf16(a1, b0, acc[1][0], 0,0,0);
    acc[1][1] = __builtin_amdgcn_mfma_f32_16x16x32_bf16(a1, b1, acc[1][1], 0,0,0);
  }

  float alv[2], arv[2];
  #pragma unroll
  for (int nt = 0; nt < 2; nt++){
    int col = cbase + nt*16 + fr;
    alv[nt] = al[by*64 + col];
    arv[nt] = ar[by*64 + col];
  }
  #pragma unroll
  for (int mt = 0; mt < 2; mt++){
    #pragma unroll
    for (int r = 0; r < 4; r++){
      float pl = acc[mt][0][r]*alv[0] + acc[mt][1][r]*alv[1];
      float pr = acc[mt][0][r]*arv[0] + acc[mt][1][r]*arv[1];
      #pragma unroll
      for (int o = 1; o < 16; o <<= 1){ pl += __shfl_xor(pl, o); pr += __shfl_xor(pr, o); }
      if (fr == 0){
        int rl = rbase + mt*16 + fg*4 + r;
        elp[nw][rl] = pl; erp[nw][rl] = pr;
      }
    }
  }
  const int NN = H*64;
  #pragma unroll
  for (int mt = 0; mt < 2; mt++){
    #pragma unroll
    for (int r = 0; r < 4; r++){
      int row = m0 + rbase + mt*16 + fg*4 + r;
      if (row < M){
        #pragma unroll
        for (int nt = 0; nt < 2; nt++)
          Cbf[(size_t)row*NN + n0 + cbase + nt*16 + fr] = f2bf(acc[mt][nt][r]);
      }
    }
  }
  __syncthreads();
  if (tid < 64){
    int row = m0 + tid;
    if (row < M){
      el[(size_t)row*H + by] = elp[0][tid] + elp[1][tid];
      er[(size_t)row*H + by] = erp[0][tid] + erp[1][tid];
    }
  }
}

// ---------------- pure gather-aggregate, H=4 (layer 1), grid-stride, 32-bit addr ----------------
__global__ __launch_bounds__(256) void k_gath4(const uint4* __restrict__ fbase, // bf16 [N][256] as uint4[N*32]
      const float* __restrict__ w4, const int* __restrict__ row_start,
      const int* __restrict__ srcp, const float* __restrict__ bias,
      __hip_bfloat16* __restrict__ outb, int N, int nwaves){
  int wv = threadIdx.x >> 6, lane = threadIdx.x & 63;
  int g = lane >> 4, j = lane & 15, h = j >> 2;
  const unsigned jo2 = (unsigned)(j << 1);   // uint4 index within row (2 per lane)

  int n = blockIdx.x*4 + wv;
  if (n >= N) return;
  int rs = row_start[n], re = row_start[n+1];

  while (true){
    int deg = re - rs;
    int nn = n + nwaves;
    int rs_n = 0, re_n = 0;
    if (nn < N){ rs_n = row_start[nn]; re_n = row_start[nn+1]; }  // prefetch next node

    float acc[16];
    #pragma unroll
    for (int k = 0; k < 16; k++) acc[k] = 0.f;
    float Sacc = 0.f;

    int i = 0;
    int full = deg & ~15;          // unguarded 16-edge quads
    for (; i < full; i += 16){
      float wb[4]; uint4 u0[4], u1[4];
      #pragma unroll
      for (int k = 0; k < 4; k++){
        unsigned e = (unsigned)(rs + i + k*4 + g);
        int sb = srcp[e];
        wb[k] = w4[(e << 2) + h];
        unsigned fi = ((unsigned)sb << 5) + jo2;
        u0[k] = fbase[fi];
        u1[k] = fbase[fi + 1];
      }
      #pragma unroll
      for (int k = 0; k < 4; k++){
        float wk = wb[k];
        Sacc += wk;
        acc[0]  += bf_lo(u0[k].x)*wk; acc[1]  += bf_hi(u0[k].x)*wk;
        acc[2]  += bf_lo(u0[k].y)*wk; acc[3]  += bf_hi(u0[k].y)*wk;
        acc[4]  += bf_lo(u0[k].z)*wk; acc[5]  += bf_hi(u0[k].z)*wk;
        acc[6]  += bf_lo(u0[k].w)*wk; acc[7]  += bf_hi(u0[k].w)*wk;
        acc[8]  += bf_lo(u1[k].x)*wk; acc[9]  += bf_hi(u1[k].x)*wk;
        acc[10] += bf_lo(u1[k].y)*wk; acc[11] += bf_hi(u1[k].y)*wk;
        acc[12] += bf_lo(u1[k].z)*wk; acc[13] += bf_hi(u1[k].z)*wk;
        acc[14] += bf_lo(u1[k].w)*wk; acc[15] += bf_hi(u1[k].w)*wk;
      }
    }
    if (i < deg){                  // guarded tail (<=15 edges)
      float wb[4]; uint4 u0[4], u1[4];
      #pragma unroll
      for (int k = 0; k < 4; k++){
        int e = i + k*4 + g;
        wb[k] = 0.f;
        u0[k] = make_uint4(0,0,0,0); u1[k] = make_uint4(0,0,0,0);
        if (e < deg){
          unsigned ee = (unsigned)(rs + e);
          int sb = srcp[ee];
          wb[k] = w4[(ee << 2) + h];
          unsigned fi = ((unsigned)sb << 5) + jo2;
          u0[k] = fbase[fi];
          u1[k] = fbase[fi + 1];
        }
      }
      #pragma unroll
      for (int k = 0; k < 4; k++){
        float wk = wb[k];
        Sacc += wk;
        acc[0]  += bf_lo(u0[k].x)*wk; acc[1]  += bf_hi(u0[k].x)*wk;
        acc[2]  += bf_lo(u0[k].y)*wk; acc[3]  += bf_hi(u0[k].y)*wk;
        acc[4]  += bf_lo(u0[k].z)*wk; acc[5]  += bf_hi(u0[k].z)*wk;
        acc[6]  += bf_lo(u0[k].w)*wk; acc[7]  += bf_hi(u0[k].w)*wk;
        acc[8]  += bf_lo(u1[k].x)*wk; acc[9]  += bf_hi(u1[k].x)*wk;
        acc[10] += bf_lo(u1[k].y)*wk; acc[11] += bf_hi(u1[k].y)*wk;
        acc[12] += bf_lo(u1[k].z)*wk; acc[13] += bf_hi(u1[k].z)*wk;
        acc[14] += bf_lo(u1[k].w)*wk; acc[15] += bf_hi(u1[k].w)*wk;
      }
    }

    #pragma unroll
    for (int k = 0; k < 16; k++){
      acc[k] += __shfl_xor(acc[k], 16);
      acc[k] += __shfl_xor(acc[k], 32);
    }
    Sacc += __shfl_xor(Sacc, 16);
    Sacc += __shfl_xor(Sacc, 32);
    if (g == 0){
      float inv = (deg > 0 && Sacc > 0.f) ? 1.f / Sacc : 0.f;
      float4 b0 = *(const float4*)&bias[j*16 + 0];
      float4 b1 = *(const float4*)&bias[j*16 + 4];
      float4 b2 = *(const float4*)&bias[j*16 + 8];
      float4 b3 = *(const float4*)&bias[j*16 + 12];
      float v[16];
      v[0]=acc[0]*inv+b0.x;  v[1]=acc[1]*inv+b0.y;  v[2]=acc[2]*inv+b0.z;  v[3]=acc[3]*inv+b0.w;
      v[4]=acc[4]*inv+b1.x;  v[5]=acc[5]*inv+b1.y;  v[6]=acc[6]*inv+b1.z;  v[7]=acc[7]*inv+b1.w;
      v[8]=acc[8]*inv+b2.x;  v[9]=acc[9]*inv+b2.y;  v[10]=acc[10]*inv+b2.z; v[11]=acc[11]*inv+b2.w;
      v[12]=acc[12]*inv+b3.x; v[13]=acc[13]*inv+b3.y; v[14]=acc[14]*inv+b3.z; v[15]=acc[15]*inv+b3.w;
      #pragma unroll
      for (int k = 0; k < 16; k++) v[k] = fmaxf(v[k], 0.f);   // relu (layer 1)
      uint4 o0, o1;
      o0.x = packbf(v[0], v[1]);   o0.y = packbf(v[2], v[3]);
      o0.z = packbf(v[4], v[5]);   o0.w = packbf(v[6], v[7]);
      o1.x = packbf(v[8], v[9]);   o1.y = packbf(v[10], v[11]);
      o1.z = packbf(v[12], v[13]); o1.w = packbf(v[14], v[15]);
      uint4* op = (uint4*)outb + (size_t)n*32 + (j << 1);
      op[0] = o0; op[1] = o1;
    }

    if (nn >= N) break;
    n = nn; rs = rs_n; re = re_n;
  }
}

// ---------------- pure gather-aggregate, H=1 (layer 2), grid-stride, 32-bit addr ----------------
__global__ __launch_bounds__(256) void k_gath1(const uint2* __restrict__ fbase, // bf16 [N][64] as uint2[N*16]
      const float* __restrict__ w1, const int* __restrict__ row_start,
      const int* __restrict__ srcp, const float* __restrict__ bias,
      float* __restrict__ out, int N, int nwaves){
  int wv = threadIdx.x >> 6, lane = threadIdx.x & 63;
  int g = lane >> 4, j = lane & 15;
  const unsigned jo = (unsigned)j;

  int n = blockIdx.x*4 + wv;
  if (n >= N) return;
  int rs = row_start[n], re = row_start[n+1];

  while (true){
    int deg = re - rs;
    int nn = n + nwaves;
    int rs_n = 0, re_n = 0;
    if (nn < N){ rs_n = row_start[nn]; re_n = row_start[nn+1]; }

    float acc[4] = {0.f, 0.f, 0.f, 0.f};
    float Sacc = 0.f;

    int i = 0;
    int full = deg & ~15;
    for (; i < full; i += 16){
      float wb[4]; uint2 u[4];
      #pragma unroll
      for (int k = 0; k < 4; k++){
        unsigned e = (unsigned)(rs + i + k*4 + g);
        int sb = srcp[e];
        wb[k] = w1[e];
        u[k] = fbase[((unsigned)sb << 4) + jo];
      }
      #pragma unroll
      for (int k = 0; k < 4; k++){
        float wk = wb[k];
        Sacc += wk;
        acc[0] += bf_lo(u[k].x)*wk; acc[1] += bf_hi(u[k].x)*wk;
        acc[2] += bf_lo(u[k].y)*wk; acc[3] += bf_hi(u[k].y)*wk;
      }
    }
    if (i < deg){
      float wb[4]; uint2 u[4];
      #pragma unroll
      for (int k = 0; k < 4; k++){
        int e = i + k*4 + g;
        wb[k] = 0.f;
        u[k] = make_uint2(0,0);
        if (e < deg){
          unsigned ee = (unsigned)(rs + e);
          int sb = srcp[ee];
          wb[k] = w1[ee];
          u[k] = fbase[((unsigned)sb << 4) + jo];
        }
      }
      #pragma unroll
      for (int k = 0; k < 4; k++){
        float wk = wb[k];
        Sacc += wk;
        acc[0] += bf_lo(u[k].x)*wk; acc[1] += bf_hi(u[k].x)*wk;
        acc[2] += bf_lo(u[k].y)*wk; acc[3] += bf_hi(u[k].y)*wk;
      }
    }

    #pragma unroll
    for (int k = 0; k < 4; k++){
      acc[k] += __shfl_xor(acc[k], 16);
      acc[k] += __shfl_xor(acc[k], 32);
    }
    Sacc += __shfl_xor(Sacc, 16);
    Sacc += __shfl_xor(Sacc, 32);
    if (g == 0){
      float inv = (deg > 0 && Sacc > 0.f) ? 1.f / Sacc : 0.f;
      float4 b = *(const float4*)&bias[j*4];
      float4 o;
      o.x = acc[0]*inv + b.x; o.y = acc[1]*inv + b.y;
      o.z = acc[2]*inv + b.z; o.w = acc[3]*inv + b.w;
      *(float4*)&out[(size_t)n*64 + j*4] = o;
    }

    if (nn >= N) break;
    n = nn; rs = rs_n; re = re_n;
  }
}

// ---------------- launch ----------------
extern "C" void kernel_launch(void* const* d_in, const int* in_sizes, int n_in,
                              void* d_out, int out_size, void* d_ws, size_t ws_size,
                              hipStream_t stream) {
  const float* emb = (const float*)d_in[0];
  const int*   src = (const int*)d_in[1];
  const int*   dst = (const int*)d_in[2];
  const float* W1  = (const float*)d_in[3];
  const float* al1 = (const float*)d_in[4];
  const float* ar1 = (const float*)d_in[5];
  const float* b1  = (const float*)d_in[6];
  const float* W2  = (const float*)d_in[7];
  const float* al2 = (const float*)d_in[8];
  const float* ar2 = (const float*)d_in[9];
  const float* b2  = (const float*)d_in[10];
  float* out = (float*)d_out;

  const int N = in_sizes[0] / 128;
  const int E = in_sizes[1];

  char* p = (char*)d_ws;
  auto alloc = [&](size_t bytes) -> void* {
    void* r = (void*)p; p += (bytes + 255) & ~(size_t)255; return r;
  };
  __hip_bfloat16* feat1b = (__hip_bfloat16*)alloc((size_t)N*256*2);
  __hip_bfloat16* h1b    = (__hip_bfloat16*)alloc((size_t)N*256*2);
  __hip_bfloat16* feat2b = (__hip_bfloat16*)alloc((size_t)N*64*2);
  float* el1             = (float*)alloc((size_t)N*4*4);
  float* er1             = (float*)alloc((size_t)N*4*4);
  float* el2             = (float*)alloc((size_t)N*4);
  float* er2             = (float*)alloc((size_t)N*4);
  int*   deg             = (int*)alloc((size_t)N*4);
  int*   row_start       = (int*)alloc((size_t)(N+1)*4);
  int*   cursor          = (int*)alloc((size_t)N*4);
  int*   blocksum        = (int*)alloc((size_t)DIV_UP(N,1024)*4);
  int*   srcp            = (int*)alloc((size_t)E*4);
  int*   dstp            = (int*)alloc((size_t)E*4);
  float* w4              = (float*)alloc((size_t)E*16);
  float* w1              = w4;   // layer-2 weights reuse (consumed before overwrite)

  const int nb = DIV_UP(N, 1024);
  const int gblocks = min(DIV_UP(N, 4), 2048);
  const int nwaves  = gblocks * 4;

  hipMemsetAsync(deg, 0, (size_t)N*4, stream);
  k_count_deg<<<DIV_UP(E,256), 256, 0, stream>>>(dst, deg, E);
  k_scan1<<<nb, 256, 0, stream>>>(deg, blocksum, N);
  k_scan2<<<1, 64, 0, stream>>>(blocksum, nb);
  k_scan3<<<nb, 256, 0, stream>>>(deg, blocksum, row_start, cursor, N);

  // Layer 1
  k_gemm_mfma<128,4,false><<<dim3(DIV_UP(N,64), 4), 256, 0, stream>>>(
      emb, W1, 256, (unsigned short*)feat1b, al1, ar1, el1, er1, N);
  k_fillw4<<<DIV_UP(E,256), 256, 0, stream>>>(dst, src, cursor, srcp, dstp,
      (const float4*)el1, (const float4*)er1, (float4*)w4, E);
  k_gath4<<<gblocks, 256, 0, stream>>>((const uint4*)feat1b, w4, row_start,
                                       srcp, b1, h1b, N, nwaves);
  // Layer 2
  k_gemm_mfma<256,1,true><<<dim3(DIV_UP(N,64), 1), 256, 0, stream>>>(
      h1b, W2, 64, (unsigned short*)feat2b, al2, ar2, el2, er2, N);
  k_edgew1<<<DIV_UP(E,256), 256, 0, stream>>>(srcp, dstp, el2, er2, w1, E);
  k_gath1<<<gblocks, 256, 0, stream>>>((const uint2*)feat2b, w1, row_start,
                                       srcp, b2, out, N, nwaves);
}

// Round 11
// 229.251 us; speedup vs baseline: 1.1515x; 1.0270x over previous
//
#include <hip/hip_runtime.h>
#include <hip/hip_bf16.h>
#include <math.h>

#define DIV_UP(a,b) (((a)+(b)-1)/(b))

typedef __attribute__((ext_vector_type(8))) short short8v;
typedef __attribute__((ext_vector_type(4))) float f32x4;

__device__ __forceinline__ float bf_lo(unsigned u){ union{unsigned x; float f;} v; v.x = u << 16; return v.f; }
__device__ __forceinline__ float bf_hi(unsigned u){ union{unsigned x; float f;} v; v.x = u & 0xffff0000u; return v.f; }
__device__ __forceinline__ unsigned short f2bf(float f){
  union{float f; unsigned u;} v; v.f = f;
  unsigned r = v.u + 0x7fff + ((v.u >> 16) & 1);   // round-nearest-even
  return (unsigned short)(r >> 16);
}
__device__ __forceinline__ unsigned packbf(float a, float b){
  return (unsigned)f2bf(a) | ((unsigned)f2bf(b) << 16);
}
__device__ __forceinline__ float lrelu(float x){ return x > 0.f ? x : 0.2f*x; }

// ---------------- CSR build ----------------
__global__ void k_count_deg(const int* __restrict__ dst, int* __restrict__ deg, int E){
  int i = blockIdx.x*blockDim.x + threadIdx.x;
  if (i < E) atomicAdd(&deg[dst[i]], 1);
}

__global__ __launch_bounds__(256) void k_scan1(const int* __restrict__ deg,
                                               int* __restrict__ blocksum, int N){
  int b = blockIdx.x;
  int base = b*1024 + threadIdx.x*4;
  int s = 0;
  if (base + 3 < N){
    int4 v = *(const int4*)&deg[base];
    s = v.x + v.y + v.z + v.w;
  } else {
    for (int i = 0; i < 4; i++){ int idx = base + i; if (idx < N) s += deg[idx]; }
  }
  #pragma unroll
  for (int o = 32; o; o >>= 1) s += __shfl_down(s, o);
  __shared__ int ws[4];
  int wid = threadIdx.x >> 6, lane = threadIdx.x & 63;
  if (lane == 0) ws[wid] = s;
  __syncthreads();
  if (threadIdx.x == 0) blocksum[b] = ws[0] + ws[1] + ws[2] + ws[3];
}

// scan3: computes own block offset from raw blocksums (nb small), then local scan.
__global__ __launch_bounds__(256) void k_scan3(const int* __restrict__ deg,
                                               const int* __restrict__ blocksum, int nb,
                                               int* __restrict__ row_start,
                                               int* __restrict__ cursor, int N){
  int b = blockIdx.x;
  __shared__ int s_boff;
  if (threadIdx.x < 64){
    int acc = 0;
    for (int base = 0; base < nb; base += 64){
      int idx = base + threadIdx.x;
      if (idx < nb && idx < b) acc += blocksum[idx];
    }
    #pragma unroll
    for (int o = 32; o; o >>= 1) acc += __shfl_down(acc, o);
    if (threadIdx.x == 0) s_boff = acc;
  }
  int base = b*1024 + threadIdx.x*4;
  int v[4];
  #pragma unroll
  for (int i = 0; i < 4; i++){ int idx = base + i; v[i] = (idx < N) ? deg[idx] : 0; }
  int s = v[0] + v[1] + v[2] + v[3];
  int lane = threadIdx.x & 63, wid = threadIdx.x >> 6;
  int inc = s;
  #pragma unroll
  for (int o = 1; o < 64; o <<= 1){ int t = __shfl_up(inc, o); if (lane >= o) inc += t; }
  __shared__ int wsum[4];
  if (lane == 63) wsum[wid] = inc;
  __syncthreads();
  int woff = 0;
  #pragma unroll
  for (int i = 0; i < 4; i++) if (i < wid) woff += wsum[i];
  int run = s_boff + woff + inc - s;
  #pragma unroll
  for (int i = 0; i < 4; i++){
    int idx = base + i;
    if (idx < N){ row_start[idx] = run; cursor[idx] = run; run += v[i]; }
  }
  if (base < N && base + 4 >= N) row_start[N] = run;
}

// fill + layer-1 edge weights fused: one pass over original edges.
__global__ void k_fillw4(const int* __restrict__ dst, const int* __restrict__ src,
                         int* __restrict__ cursor, int* __restrict__ srcp,
                         int* __restrict__ dstp,
                         const float4* __restrict__ el4, const float4* __restrict__ er4,
                         float4* __restrict__ w4, int E){
  int i = blockIdx.x*blockDim.x + threadIdx.x;
  if (i < E){
    int d = dst[i], s = src[i];
    int p = atomicAdd(&cursor[d], 1);
    srcp[p] = s; dstp[p] = d;
    float4 l = el4[s], r = er4[d];
    float4 w;
    w.x = __expf(lrelu(l.x + r.x));
    w.y = __expf(lrelu(l.y + r.y));
    w.z = __expf(lrelu(l.z + r.z));
    w.w = __expf(lrelu(l.w + r.w));
    w4[p] = w;
  }
}

// layer-2 edge weights
__global__ void k_edgew1(const int* __restrict__ srcp, const int* __restrict__ dstp,
                         const float* __restrict__ el, const float* __restrict__ er,
                         float* __restrict__ w1, int E){
  int i = blockIdx.x*blockDim.x + threadIdx.x;
  if (i < E) w1[i] = __expf(lrelu(el[srcp[i]] + er[dstp[i]]));
}

// ---------------- GEMM1: A staged once, loop 4 heads (Bt restaged per head) ----------------
__global__ __launch_bounds__(256) void k_gemm1loop(const float* __restrict__ A, // emb [M][128]
      const float* __restrict__ B,      // W1 [128][256]
      unsigned short* __restrict__ Cbf, // feat1b [M][256]
      const float* __restrict__ al, const float* __restrict__ ar,   // [256]
      float* __restrict__ el, float* __restrict__ er, int M){       // [M][4]
  __shared__ alignas(16) __hip_bfloat16 At[64][136];
  __shared__ alignas(16) __hip_bfloat16 Bt[64][136];
  __shared__ float elp[2][64], erp[2][64];
  const int tid = threadIdx.x;
  const int lane = tid & 63, w = tid >> 6;
  const int mw = w >> 1, nw = w & 1;
  const int m0 = blockIdx.x * 64;
  const int rbase = mw*32, cbase = nw*32;
  const int fr = lane & 15, fg = lane >> 4;

  // stage A once: 64 x 128 fp32 -> bf16
  #pragma unroll
  for (int i = 0; i < 8; i++){
    int q = tid + i*256;
    int row = q >> 5, c4 = q & 31;
    float4 a = make_float4(0.f,0.f,0.f,0.f);
    if (m0 + row < M) a = *(const float4*)&A[(size_t)(m0+row)*128 + c4*4];
    *(uint2*)&At[row][c4*4] = make_uint2(packbf(a.x,a.y), packbf(a.z,a.w));
  }

  for (int by = 0; by < 4; by++){
    int n0 = by * 64;
    __syncthreads();                    // A staged / prev iter's Bt+elp reads done
    #pragma unroll
    for (int i = 0; i < 8; i++){        // Bt[c][k] = W1[k][n0+c]
      int q = tid + i*256;
      int c = q & 63, k4 = q >> 6;
      float b0 = B[(size_t)(k4*4+0)*256 + n0 + c];
      float b1 = B[(size_t)(k4*4+1)*256 + n0 + c];
      float b2 = B[(size_t)(k4*4+2)*256 + n0 + c];
      float b3 = B[(size_t)(k4*4+3)*256 + n0 + c];
      *(uint2*)&Bt[c][k4*4] = make_uint2(packbf(b0,b1), packbf(b2,b3));
    }
    __syncthreads();

    f32x4 acc[2][2];
    #pragma unroll
    for (int i = 0; i < 2; i++)
      #pragma unroll
      for (int jj = 0; jj < 2; jj++)
        #pragma unroll
        for (int r = 0; r < 4; r++) acc[i][jj][r] = 0.f;

    #pragma unroll
    for (int ks = 0; ks < 4; ks++){
      short8v a0 = *(const short8v*)&At[rbase + fr     ][ks*32 + fg*8];
      short8v a1 = *(const short8v*)&At[rbase + 16 + fr][ks*32 + fg*8];
      short8v b0 = *(const short8v*)&Bt[cbase + fr     ][ks*32 + fg*8];
      short8v b1 = *(const short8v*)&Bt[cbase + 16 + fr][ks*32 + fg*8];
      acc[0][0] = __builtin_amdgcn_mfma_f32_16x16x32_bf16(a0, b0, acc[0][0], 0,0,0);
      acc[0][1] = __builtin_amdgcn_mfma_f32_16x16x32_bf16(a0, b1, acc[0][1], 0,0,0);
      acc[1][0] = __builtin_amdgcn_mfma_f32_16x16x32_bf16(a1, b0, acc[1][0], 0,0,0);
      acc[1][1] = __builtin_amdgcn_mfma_f32_16x16x32_bf16(a1, b1, acc[1][1], 0,0,0);
    }

    float alv[2], arv[2];
    #pragma unroll
    for (int nt = 0; nt < 2; nt++){
      int col = cbase + nt*16 + fr;
      alv[nt] = al[n0 + col];
      arv[nt] = ar[n0 + col];
    }
    #pragma unroll
    for (int mt = 0; mt < 2; mt++){
      #pragma unroll
      for (int r = 0; r < 4; r++){
        float pl = acc[mt][0][r]*alv[0] + acc[mt][1][r]*alv[1];
        float pr = acc[mt][0][r]*arv[0] + acc[mt][1][r]*arv[1];
        #pragma unroll
        for (int o = 1; o < 16; o <<= 1){ pl += __shfl_xor(pl, o); pr += __shfl_xor(pr, o); }
        if (fr == 0){
          int rl = rbase + mt*16 + fg*4 + r;
          elp[nw][rl] = pl; erp[nw][rl] = pr;
        }
      }
    }
    #pragma unroll
    for (int mt = 0; mt < 2; mt++){
      #pragma unroll
      for (int r = 0; r < 4; r++){
        int row = m0 + rbase + mt*16 + fg*4 + r;
        if (row < M){
          #pragma unroll
          for (int nt = 0; nt < 2; nt++)
            Cbf[(size_t)row*256 + n0 + cbase + nt*16 + fr] = f2bf(acc[mt][nt][r]);
        }
      }
    }
    __syncthreads();
    if (tid < 64){
      int row = m0 + tid;
      if (row < M){
        el[(size_t)row*4 + by] = elp[0][tid] + elp[1][tid];
        er[(size_t)row*4 + by] = erp[0][tid] + erp[1][tid];
      }
    }
  }
}

// ---------------- GEMM2 (layer 2), 64x64, full-K LDS, fused el/er ----------------
template<int K, int H, bool ABF>
__global__ __launch_bounds__(256) void k_gemm_mfma(const void* __restrict__ Av,
      const float* __restrict__ B, int ldb,
      unsigned short* __restrict__ Cbf,
      const float* __restrict__ al, const float* __restrict__ ar,
      float* __restrict__ el, float* __restrict__ er, int M){
  constexpr int KP = K + 8;
  __shared__ alignas(16) __hip_bfloat16 At[64][KP];
  __shared__ alignas(16) __hip_bfloat16 Bt[64][KP];
  __shared__ float elp[2][64], erp[2][64];
  const int tid = threadIdx.x;
  const int lane = tid & 63, w = tid >> 6;
  const int mw = w >> 1, nw = w & 1;
  const int m0 = blockIdx.x * 64, by = blockIdx.y, n0 = by * 64;

  if constexpr (!ABF){
    const float* A = (const float*)Av;
    #pragma unroll
    for (int i = 0; i < K/16; i++){
      int q = tid + i*256;
      int row = q / (K/4), c4 = q % (K/4);
      float4 a = make_float4(0.f,0.f,0.f,0.f);
      if (m0 + row < M) a = *(const float4*)&A[(size_t)(m0+row)*K + c4*4];
      *(uint2*)&At[row][c4*4] = make_uint2(packbf(a.x,a.y), packbf(a.z,a.w));
    }
  } else {
    const __hip_bfloat16* A = (const __hip_bfloat16*)Av;
    #pragma unroll
    for (int i = 0; i < K/32; i++){
      int q = tid + i*256;
      int row = q / (K/8), c8 = q % (K/8);
      uint4 u = make_uint4(0,0,0,0);
      if (m0 + row < M) u = *(const uint4*)&A[(size_t)(m0+row)*K + c8*8];
      *(uint4*)&At[row][c8*8] = u;
    }
  }
  #pragma unroll
  for (int i = 0; i < K/16; i++){
    int q = tid + i*256;
    int c = q & 63, k4 = q >> 6;
    float b0 = B[(size_t)(k4*4+0)*ldb + n0 + c];
    float b1 = B[(size_t)(k4*4+1)*ldb + n0 + c];
    float b2 = B[(size_t)(k4*4+2)*ldb + n0 + c];
    float b3 = B[(size_t)(k4*4+3)*ldb + n0 + c];
    *(uint2*)&Bt[c][k4*4] = make_uint2(packbf(b0,b1), packbf(b2,b3));
  }
  __syncthreads();

  f32x4 acc[2][2];
  #pragma unroll
  for (int i = 0; i < 2; i++)
    #pragma unroll
    for (int j = 0; j < 2; j++)
      #pragma unroll
      for (int r = 0; r < 4; r++) acc[i][j][r] = 0.f;

  const int rbase = mw*32, cbase = nw*32;
  const int fr = lane & 15, fg = lane >> 4;
  #pragma unroll
  for (int ks = 0; ks < K/32; ks++){
    short8v a0 = *(const short8v*)&At[rbase + fr     ][ks*32 + fg*8];
    short8v a1 = *(const short8v*)&At[rbase + 16 + fr][ks*32 + fg*8];
    short8v b0 = *(const short8v*)&Bt[cbase + fr     ][ks*32 + fg*8];
    short8v b1 = *(const short8v*)&Bt[cbase + 16 + fr][ks*32 + fg*8];
    acc[0][0] = __builtin_amdgcn_mfma_f32_16x16x32_bf16(a0, b0, acc[0][0], 0,0,0);
    acc[0][1] = __builtin_amdgcn_mfma_f32_16x16x32_bf16(a0, b1, acc[0][1], 0,0,0);
    acc[1][0] = __builtin_amdgcn_mfma_f32_16x16x32_bf16(a1, b0, acc[1][0], 0,0,0);
    acc[1][1] = __builtin_amdgcn_mfma_f32_16x16x32_bf16(a1, b1, acc[1][1], 0,0,0);
  }

  float alv[2], arv[2];
  #pragma unroll
  for (int nt = 0; nt < 2; nt++){
    int col = cbase + nt*16 + fr;
    alv[nt] = al[by*64 + col];
    arv[nt] = ar[by*64 + col];
  }
  #pragma unroll
  for (int mt = 0; mt < 2; mt++){
    #pragma unroll
    for (int r = 0; r < 4; r++){
      float pl = acc[mt][0][r]*alv[0] + acc[mt][1][r]*alv[1];
      float pr = acc[mt][0][r]*arv[0] + acc[mt][1][r]*arv[1];
      #pragma unroll
      for (int o = 1; o < 16; o <<= 1){ pl += __shfl_xor(pl, o); pr += __shfl_xor(pr, o); }
      if (fr == 0){
        int rl = rbase + mt*16 + fg*4 + r;
        elp[nw][rl] = pl; erp[nw][rl] = pr;
      }
    }
  }
  const int NN = H*64;
  #pragma unroll
  for (int mt = 0; mt < 2; mt++){
    #pragma unroll
    for (int r = 0; r < 4; r++){
      int row = m0 + rbase + mt*16 + fg*4 + r;
      if (row < M){
        #pragma unroll
        for (int nt = 0; nt < 2; nt++)
          Cbf[(size_t)row*NN + n0 + cbase + nt*16 + fr] = f2bf(acc[mt][nt][r]);
      }
    }
  }
  __syncthreads();
  if (tid < 64){
    int row = m0 + tid;
    if (row < M){
      el[(size_t)row*H + by] = elp[0][tid] + elp[1][tid];
      er[(size_t)row*H + by] = erp[0][tid] + erp[1][tid];
    }
  }
}

// ---------------- pure gather-aggregate, H=4 (layer 1), grid-stride, 32-bit addr ----------------
__global__ __launch_bounds__(256) void k_gath4(const uint4* __restrict__ fbase, // bf16 [N][256] as uint4[N*32]
      const float* __restrict__ w4, const int* __restrict__ row_start,
      const int* __restrict__ srcp, const float* __restrict__ bias,
      __hip_bfloat16* __restrict__ outb, int N, int nwaves){
  int wv = threadIdx.x >> 6, lane = threadIdx.x & 63;
  int g = lane >> 4, j = lane & 15, h = j >> 2;
  const unsigned jo2 = (unsigned)(j << 1);   // uint4 index within row (2 per lane)

  int n = blockIdx.x*4 + wv;
  if (n >= N) return;
  int rs = row_start[n], re = row_start[n+1];

  while (true){
    int deg = re - rs;
    int nn = n + nwaves;
    int rs_n = 0, re_n = 0;
    if (nn < N){ rs_n = row_start[nn]; re_n = row_start[nn+1]; }  // prefetch next node

    float acc[16];
    #pragma unroll
    for (int k = 0; k < 16; k++) acc[k] = 0.f;
    float Sacc = 0.f;

    int i = 0;
    int full = deg & ~15;          // unguarded 16-edge quads
    for (; i < full; i += 16){
      float wb[4]; uint4 u0[4], u1[4];
      #pragma unroll
      for (int k = 0; k < 4; k++){
        unsigned e = (unsigned)(rs + i + k*4 + g);
        int sb = srcp[e];
        wb[k] = w4[(e << 2) + h];
        unsigned fi = ((unsigned)sb << 5) + jo2;
        u0[k] = fbase[fi];
        u1[k] = fbase[fi + 1];
      }
      #pragma unroll
      for (int k = 0; k < 4; k++){
        float wk = wb[k];
        Sacc += wk;
        acc[0]  += bf_lo(u0[k].x)*wk; acc[1]  += bf_hi(u0[k].x)*wk;
        acc[2]  += bf_lo(u0[k].y)*wk; acc[3]  += bf_hi(u0[k].y)*wk;
        acc[4]  += bf_lo(u0[k].z)*wk; acc[5]  += bf_hi(u0[k].z)*wk;
        acc[6]  += bf_lo(u0[k].w)*wk; acc[7]  += bf_hi(u0[k].w)*wk;
        acc[8]  += bf_lo(u1[k].x)*wk; acc[9]  += bf_hi(u1[k].x)*wk;
        acc[10] += bf_lo(u1[k].y)*wk; acc[11] += bf_hi(u1[k].y)*wk;
        acc[12] += bf_lo(u1[k].z)*wk; acc[13] += bf_hi(u1[k].z)*wk;
        acc[14] += bf_lo(u1[k].w)*wk; acc[15] += bf_hi(u1[k].w)*wk;
      }
    }
    if (i < deg){                  // guarded tail (<=15 edges)
      float wb[4]; uint4 u0[4], u1[4];
      #pragma unroll
      for (int k = 0; k < 4; k++){
        int e = i + k*4 + g;
        wb[k] = 0.f;
        u0[k] = make_uint4(0,0,0,0); u1[k] = make_uint4(0,0,0,0);
        if (e < deg){
          unsigned ee = (unsigned)(rs + e);
          int sb = srcp[ee];
          wb[k] = w4[(ee << 2) + h];
          unsigned fi = ((unsigned)sb << 5) + jo2;
          u0[k] = fbase[fi];
          u1[k] = fbase[fi + 1];
        }
      }
      #pragma unroll
      for (int k = 0; k < 4; k++){
        float wk = wb[k];
        Sacc += wk;
        acc[0]  += bf_lo(u0[k].x)*wk; acc[1]  += bf_hi(u0[k].x)*wk;
        acc[2]  += bf_lo(u0[k].y)*wk; acc[3]  += bf_hi(u0[k].y)*wk;
        acc[4]  += bf_lo(u0[k].z)*wk; acc[5]  += bf_hi(u0[k].z)*wk;
        acc[6]  += bf_lo(u0[k].w)*wk; acc[7]  += bf_hi(u0[k].w)*wk;
        acc[8]  += bf_lo(u1[k].x)*wk; acc[9]  += bf_hi(u1[k].x)*wk;
        acc[10] += bf_lo(u1[k].y)*wk; acc[11] += bf_hi(u1[k].y)*wk;
        acc[12] += bf_lo(u1[k].z)*wk; acc[13] += bf_hi(u1[k].z)*wk;
        acc[14] += bf_lo(u1[k].w)*wk; acc[15] += bf_hi(u1[k].w)*wk;
      }
    }

    #pragma unroll
    for (int k = 0; k < 16; k++){
      acc[k] += __shfl_xor(acc[k], 16);
      acc[k] += __shfl_xor(acc[k], 32);
    }
    Sacc += __shfl_xor(Sacc, 16);
    Sacc += __shfl_xor(Sacc, 32);
    if (g == 0){
      float inv = (deg > 0 && Sacc > 0.f) ? 1.f / Sacc : 0.f;
      float4 b0 = *(const float4*)&bias[j*16 + 0];
      float4 b1 = *(const float4*)&bias[j*16 + 4];
      float4 b2 = *(const float4*)&bias[j*16 + 8];
      float4 b3 = *(const float4*)&bias[j*16 + 12];
      float v[16];
      v[0]=acc[0]*inv+b0.x;  v[1]=acc[1]*inv+b0.y;  v[2]=acc[2]*inv+b0.z;  v[3]=acc[3]*inv+b0.w;
      v[4]=acc[4]*inv+b1.x;  v[5]=acc[5]*inv+b1.y;  v[6]=acc[6]*inv+b1.z;  v[7]=acc[7]*inv+b1.w;
      v[8]=acc[8]*inv+b2.x;  v[9]=acc[9]*inv+b2.y;  v[10]=acc[10]*inv+b2.z; v[11]=acc[11]*inv+b2.w;
      v[12]=acc[12]*inv+b3.x; v[13]=acc[13]*inv+b3.y; v[14]=acc[14]*inv+b3.z; v[15]=acc[15]*inv+b3.w;
      #pragma unroll
      for (int k = 0; k < 16; k++) v[k] = fmaxf(v[k], 0.f);   // relu (layer 1)
      uint4 o0, o1;
      o0.x = packbf(v[0], v[1]);   o0.y = packbf(v[2], v[3]);
      o0.z = packbf(v[4], v[5]);   o0.w = packbf(v[6], v[7]);
      o1.x = packbf(v[8], v[9]);   o1.y = packbf(v[10], v[11]);
      o1.z = packbf(v[12], v[13]); o1.w = packbf(v[14], v[15]);
      uint4* op = (uint4*)outb + (size_t)n*32 + (j << 1);
      op[0] = o0; op[1] = o1;
    }

    if (nn >= N) break;
    n = nn; rs = rs_n; re = re_n;
  }
}

// ---------------- pure gather-aggregate, H=1 (layer 2), grid-stride, 32-bit addr ----------------
__global__ __launch_bounds__(256) void k_gath1(const uint2* __restrict__ fbase, // bf16 [N][64] as uint2[N*16]
      const float* __restrict__ w1, const int* __restrict__ row_start,
      const int* __restrict__ srcp, const float* __restrict__ bias,
      float* __restrict__ out, int N, int nwaves){
  int wv = threadIdx.x >> 6, lane = threadIdx.x & 63;
  int g = lane >> 4, j = lane & 15;
  const unsigned jo = (unsigned)j;

  int n = blockIdx.x*4 + wv;
  if (n >= N) return;
  int rs = row_start[n], re = row_start[n+1];

  while (true){
    int deg = re - rs;
    int nn = n + nwaves;
    int rs_n = 0, re_n = 0;
    if (nn < N){ rs_n = row_start[nn]; re_n = row_start[nn+1]; }

    float acc[4] = {0.f, 0.f, 0.f, 0.f};
    float Sacc = 0.f;

    int i = 0;
    int full = deg & ~15;
    for (; i < full; i += 16){
      float wb[4]; uint2 u[4];
      #pragma unroll
      for (int k = 0; k < 4; k++){
        unsigned e = (unsigned)(rs + i + k*4 + g);
        int sb = srcp[e];
        wb[k] = w1[e];
        u[k] = fbase[((unsigned)sb << 4) + jo];
      }
      #pragma unroll
      for (int k = 0; k < 4; k++){
        float wk = wb[k];
        Sacc += wk;
        acc[0] += bf_lo(u[k].x)*wk; acc[1] += bf_hi(u[k].x)*wk;
        acc[2] += bf_lo(u[k].y)*wk; acc[3] += bf_hi(u[k].y)*wk;
      }
    }
    if (i < deg){
      float wb[4]; uint2 u[4];
      #pragma unroll
      for (int k = 0; k < 4; k++){
        int e = i + k*4 + g;
        wb[k] = 0.f;
        u[k] = make_uint2(0,0);
        if (e < deg){
          unsigned ee = (unsigned)(rs + e);
          int sb = srcp[ee];
          wb[k] = w1[ee];
          u[k] = fbase[((unsigned)sb << 4) + jo];
        }
      }
      #pragma unroll
      for (int k = 0; k < 4; k++){
        float wk = wb[k];
        Sacc += wk;
        acc[0] += bf_lo(u[k].x)*wk; acc[1] += bf_hi(u[k].x)*wk;
        acc[2] += bf_lo(u[k].y)*wk; acc[3] += bf_hi(u[k].y)*wk;
      }
    }

    #pragma unroll
    for (int k = 0; k < 4; k++){
      acc[k] += __shfl_xor(acc[k], 16);
      acc[k] += __shfl_xor(acc[k], 32);
    }
    Sacc += __shfl_xor(Sacc, 16);
    Sacc += __shfl_xor(Sacc, 32);
    if (g == 0){
      float inv = (deg > 0 && Sacc > 0.f) ? 1.f / Sacc : 0.f;
      float4 b = *(const float4*)&bias[j*4];
      float4 o;
      o.x = acc[0]*inv + b.x; o.y = acc[1]*inv + b.y;
      o.z = acc[2]*inv + b.z; o.w = acc[3]*inv + b.w;
      *(float4*)&out[(size_t)n*64 + j*4] = o;
    }

    if (nn >= N) break;
    n = nn; rs = rs_n; re = re_n;
  }
}

// ---------------- launch ----------------
extern "C" void kernel_launch(void* const* d_in, const int* in_sizes, int n_in,
                              void* d_out, int out_size, void* d_ws, size_t ws_size,
                              hipStream_t stream) {
  const float* emb = (const float*)d_in[0];
  const int*   src = (const int*)d_in[1];
  const int*   dst = (const int*)d_in[2];
  const float* W1  = (const float*)d_in[3];
  const float* al1 = (const float*)d_in[4];
  const float* ar1 = (const float*)d_in[5];
  const float* b1  = (const float*)d_in[6];
  const float* W2  = (const float*)d_in[7];
  const float* al2 = (const float*)d_in[8];
  const float* ar2 = (const float*)d_in[9];
  const float* b2  = (const float*)d_in[10];
  float* out = (float*)d_out;

  const int N = in_sizes[0] / 128;
  const int E = in_sizes[1];

  char* p = (char*)d_ws;
  auto alloc = [&](size_t bytes) -> void* {
    void* r = (void*)p; p += (bytes + 255) & ~(size_t)255; return r;
  };
  __hip_bfloat16* feat1b = (__hip_bfloat16*)alloc((size_t)N*256*2);
  __hip_bfloat16* h1b    = (__hip_bfloat16*)alloc((size_t)N*256*2);
  __hip_bfloat16* feat2b = (__hip_bfloat16*)alloc((size_t)N*64*2);
  float* el1             = (float*)alloc((size_t)N*4*4);
  float* er1             = (float*)alloc((size_t)N*4*4);
  float* el2             = (float*)alloc((size_t)N*4);
  float* er2             = (float*)alloc((size_t)N*4);
  int*   deg             = (int*)alloc((size_t)N*4);
  int*   row_start       = (int*)alloc((size_t)(N+1)*4);
  int*   cursor          = (int*)alloc((size_t)N*4);
  int*   blocksum        = (int*)alloc((size_t)DIV_UP(N,1024)*4);
  int*   srcp            = (int*)alloc((size_t)E*4);
  int*   dstp            = (int*)alloc((size_t)E*4);
  float* w4              = (float*)alloc((size_t)E*16);
  float* w1              = w4;   // layer-2 weights reuse (consumed before overwrite)

  const int nb = DIV_UP(N, 1024);
  const int gblocks = min(DIV_UP(N, 4), 2048);
  const int nwaves  = gblocks * 4;

  hipMemsetAsync(deg, 0, (size_t)N*4, stream);
  k_count_deg<<<DIV_UP(E,256), 256, 0, stream>>>(dst, deg, E);
  k_scan1<<<nb, 256, 0, stream>>>(deg, blocksum, N);
  k_scan3<<<nb, 256, 0, stream>>>(deg, blocksum, nb, row_start, cursor, N);

  // Layer 1
  k_gemm1loop<<<DIV_UP(N,64), 256, 0, stream>>>(emb, W1, (unsigned short*)feat1b,
                                                al1, ar1, el1, er1, N);
  k_fillw4<<<DIV_UP(E,256), 256, 0, stream>>>(dst, src, cursor, srcp, dstp,
      (const float4*)el1, (const float4*)er1, (float4*)w4, E);
  k_gath4<<<gblocks, 256, 0, stream>>>((const uint4*)feat1b, w4, row_start,
                                       srcp, b1, h1b, N, nwaves);
  // Layer 2
  k_gemm_mfma<256,1,true><<<dim3(DIV_UP(N,64), 1), 256, 0, stream>>>(
      h1b, W2, 64, (unsigned short*)feat2b, al2, ar2, el2, er2, N);
  k_edgew1<<<DIV_UP(E,256), 256, 0, stream>>>(srcp, dstp, el2, er2, w1, E);
  k_gath1<<<gblocks, 256, 0, stream>>>((const uint2*)feat2b, w1, row_start,
                                       srcp, b2, out, N, nwaves);
}

// Round 12
// 200.352 us; speedup vs baseline: 1.3176x; 1.1442x over previous
//
#include <hip/hip_runtime.h>
#include <hip/hip_bf16.h>
#include <math.h>

#define DIV_UP(a,b) (((a)+(b)-1)/(b))

typedef __attribute__((ext_vector_type(8))) short short8v;
typedef __attribute__((ext_vector_type(4))) float f32x4;

__device__ __forceinline__ float bf_lo(unsigned u){ union{unsigned x; float f;} v; v.x = u << 16; return v.f; }
__device__ __forceinline__ float bf_hi(unsigned u){ union{unsigned x; float f;} v; v.x = u & 0xffff0000u; return v.f; }
__device__ __forceinline__ unsigned short f2bf(float f){
  union{float f; unsigned u;} v; v.f = f;
  unsigned r = v.u + 0x7fff + ((v.u >> 16) & 1);   // round-nearest-even
  return (unsigned short)(r >> 16);
}
__device__ __forceinline__ unsigned packbf(float a, float b){
  return (unsigned)f2bf(a) | ((unsigned)f2bf(b) << 16);
}
__device__ __forceinline__ float lrelu(float x){ return x > 0.f ? x : 0.2f*x; }

// ---------------- CSR scan ----------------
__global__ __launch_bounds__(256) void k_scan1(const int* __restrict__ deg,
                                               int* __restrict__ blocksum, int N){
  int b = blockIdx.x;
  int base = b*1024 + threadIdx.x*4;
  int s = 0;
  if (base + 3 < N){
    int4 v = *(const int4*)&deg[base];
    s = v.x + v.y + v.z + v.w;
  } else {
    for (int i = 0; i < 4; i++){ int idx = base + i; if (idx < N) s += deg[idx]; }
  }
  #pragma unroll
  for (int o = 32; o; o >>= 1) s += __shfl_down(s, o);
  __shared__ int ws[4];
  int wid = threadIdx.x >> 6, lane = threadIdx.x & 63;
  if (lane == 0) ws[wid] = s;
  __syncthreads();
  if (threadIdx.x == 0) blocksum[b] = ws[0] + ws[1] + ws[2] + ws[3];
}

// scan3: computes own block offset from raw blocksums (nb small), then local scan.
__global__ __launch_bounds__(256) void k_scan3(const int* __restrict__ deg,
                                               const int* __restrict__ blocksum, int nb,
                                               int* __restrict__ row_start,
                                               int* __restrict__ cursor, int N){
  int b = blockIdx.x;
  __shared__ int s_boff;
  if (threadIdx.x < 64){
    int acc = 0;
    for (int base = 0; base < nb; base += 64){
      int idx = base + threadIdx.x;
      if (idx < nb && idx < b) acc += blocksum[idx];
    }
    #pragma unroll
    for (int o = 32; o; o >>= 1) acc += __shfl_down(acc, o);
    if (threadIdx.x == 0) s_boff = acc;
  }
  int base = b*1024 + threadIdx.x*4;
  int v[4];
  #pragma unroll
  for (int i = 0; i < 4; i++){ int idx = base + i; v[i] = (idx < N) ? deg[idx] : 0; }
  int s = v[0] + v[1] + v[2] + v[3];
  int lane = threadIdx.x & 63, wid = threadIdx.x >> 6;
  int inc = s;
  #pragma unroll
  for (int o = 1; o < 64; o <<= 1){ int t = __shfl_up(inc, o); if (lane >= o) inc += t; }
  __shared__ int wsum[4];
  if (lane == 63) wsum[wid] = inc;
  __syncthreads();
  int woff = 0;
  #pragma unroll
  for (int i = 0; i < 4; i++) if (i < wid) woff += wsum[i];
  int run = s_boff + woff + inc - s;
  #pragma unroll
  for (int i = 0; i < 4; i++){
    int idx = base + i;
    if (idx < N){ row_start[idx] = run; cursor[idx] = run; run += v[i]; }
  }
  if (base < N && base + 4 >= N) row_start[N] = run;
}

// fill + layer-1 edge weights fused: one pass over original edges.
__global__ void k_fillw4(const int* __restrict__ dst, const int* __restrict__ src,
                         int* __restrict__ cursor, int* __restrict__ srcp,
                         const float4* __restrict__ el4, const float4* __restrict__ er4,
                         float4* __restrict__ w4, int E){
  int i = blockIdx.x*blockDim.x + threadIdx.x;
  if (i < E){
    int d = dst[i], s = src[i];
    int p = atomicAdd(&cursor[d], 1);
    srcp[p] = s;
    float4 l = el4[s], r = er4[d];
    float4 w;
    w.x = __expf(lrelu(l.x + r.x));
    w.y = __expf(lrelu(l.y + r.y));
    w.z = __expf(lrelu(l.z + r.z));
    w.w = __expf(lrelu(l.w + r.w));
    w4[p] = w;
  }
}

// ---------------- GEMM1 (A staged once, 4-head loop) fused with degree count ----------------
// blocks [0, gemmBlocks): GEMM1 64-row tile.  blocks [gemmBlocks, ...): count_deg.
__global__ __launch_bounds__(256) void k_gemm1_count(const float* __restrict__ A, // emb [M][128]
      const float* __restrict__ B,      // W1 [128][256]
      unsigned short* __restrict__ Cbf, // feat1b [M][256]
      const float* __restrict__ al, const float* __restrict__ ar,   // [256]
      float* __restrict__ el, float* __restrict__ er, int M,        // [M][4]
      const int* __restrict__ dst, int* __restrict__ deg, int E, int gemmBlocks){
  __shared__ alignas(16) __hip_bfloat16 At[64][136];
  __shared__ alignas(16) __hip_bfloat16 Bt[64][136];
  __shared__ float elp[2][64], erp[2][64];

  if (blockIdx.x >= gemmBlocks){
    int i = (blockIdx.x - gemmBlocks)*256 + threadIdx.x;
    if (i < E) atomicAdd(&deg[dst[i]], 1);
    return;
  }

  const int tid = threadIdx.x;
  const int lane = tid & 63, w = tid >> 6;
  const int mw = w >> 1, nw = w & 1;
  const int m0 = blockIdx.x * 64;
  const int rbase = mw*32, cbase = nw*32;
  const int fr = lane & 15, fg = lane >> 4;

  // stage A once: 64 x 128 fp32 -> bf16
  #pragma unroll
  for (int i = 0; i < 8; i++){
    int q = tid + i*256;
    int row = q >> 5, c4 = q & 31;
    float4 a = make_float4(0.f,0.f,0.f,0.f);
    if (m0 + row < M) a = *(const float4*)&A[(size_t)(m0+row)*128 + c4*4];
    *(uint2*)&At[row][c4*4] = make_uint2(packbf(a.x,a.y), packbf(a.z,a.w));
  }

  for (int by = 0; by < 4; by++){
    int n0 = by * 64;
    __syncthreads();                    // A staged / prev iter's Bt+elp reads done
    #pragma unroll
    for (int i = 0; i < 8; i++){        // Bt[c][k] = W1[k][n0+c]
      int q = tid + i*256;
      int c = q & 63, k4 = q >> 6;
      float b0 = B[(size_t)(k4*4+0)*256 + n0 + c];
      float b1 = B[(size_t)(k4*4+1)*256 + n0 + c];
      float b2 = B[(size_t)(k4*4+2)*256 + n0 + c];
      float b3 = B[(size_t)(k4*4+3)*256 + n0 + c];
      *(uint2*)&Bt[c][k4*4] = make_uint2(packbf(b0,b1), packbf(b2,b3));
    }
    __syncthreads();

    f32x4 acc[2][2];
    #pragma unroll
    for (int i = 0; i < 2; i++)
      #pragma unroll
      for (int jj = 0; jj < 2; jj++)
        #pragma unroll
        for (int r = 0; r < 4; r++) acc[i][jj][r] = 0.f;

    #pragma unroll
    for (int ks = 0; ks < 4; ks++){
      short8v a0 = *(const short8v*)&At[rbase + fr     ][ks*32 + fg*8];
      short8v a1 = *(const short8v*)&At[rbase + 16 + fr][ks*32 + fg*8];
      short8v b0 = *(const short8v*)&Bt[cbase + fr     ][ks*32 + fg*8];
      short8v b1 = *(const short8v*)&Bt[cbase + 16 + fr][ks*32 + fg*8];
      acc[0][0] = __builtin_amdgcn_mfma_f32_16x16x32_bf16(a0, b0, acc[0][0], 0,0,0);
      acc[0][1] = __builtin_amdgcn_mfma_f32_16x16x32_bf16(a0, b1, acc[0][1], 0,0,0);
      acc[1][0] = __builtin_amdgcn_mfma_f32_16x16x32_bf16(a1, b0, acc[1][0], 0,0,0);
      acc[1][1] = __builtin_amdgcn_mfma_f32_16x16x32_bf16(a1, b1, acc[1][1], 0,0,0);
    }

    float alv[2], arv[2];
    #pragma unroll
    for (int nt = 0; nt < 2; nt++){
      int col = cbase + nt*16 + fr;
      alv[nt] = al[n0 + col];
      arv[nt] = ar[n0 + col];
    }
    #pragma unroll
    for (int mt = 0; mt < 2; mt++){
      #pragma unroll
      for (int r = 0; r < 4; r++){
        float pl = acc[mt][0][r]*alv[0] + acc[mt][1][r]*alv[1];
        float pr = acc[mt][0][r]*arv[0] + acc[mt][1][r]*arv[1];
        #pragma unroll
        for (int o = 1; o < 16; o <<= 1){ pl += __shfl_xor(pl, o); pr += __shfl_xor(pr, o); }
        if (fr == 0){
          int rl = rbase + mt*16 + fg*4 + r;
          elp[nw][rl] = pl; erp[nw][rl] = pr;
        }
      }
    }
    #pragma unroll
    for (int mt = 0; mt < 2; mt++){
      #pragma unroll
      for (int r = 0; r < 4; r++){
        int row = m0 + rbase + mt*16 + fg*4 + r;
        if (row < M){
          #pragma unroll
          for (int nt = 0; nt < 2; nt++)
            Cbf[(size_t)row*256 + n0 + cbase + nt*16 + fr] = f2bf(acc[mt][nt][r]);
        }
      }
    }
    __syncthreads();
    if (tid < 64){
      int row = m0 + tid;
      if (row < M){
        el[(size_t)row*4 + by] = elp[0][tid] + elp[1][tid];
        er[(size_t)row*4 + by] = erp[0][tid] + erp[1][tid];
      }
    }
  }
}

// ---------------- GEMM2 (layer 2), 64x64, full-K LDS, fused el/er ----------------
template<int K, int H, bool ABF>
__global__ __launch_bounds__(256) void k_gemm_mfma(const void* __restrict__ Av,
      const float* __restrict__ B, int ldb,
      unsigned short* __restrict__ Cbf,
      const float* __restrict__ al, const float* __restrict__ ar,
      float* __restrict__ el, float* __restrict__ er, int M){
  constexpr int KP = K + 8;
  __shared__ alignas(16) __hip_bfloat16 At[64][KP];
  __shared__ alignas(16) __hip_bfloat16 Bt[64][KP];
  __shared__ float elp[2][64], erp[2][64];
  const int tid = threadIdx.x;
  const int lane = tid & 63, w = tid >> 6;
  const int mw = w >> 1, nw = w & 1;
  const int m0 = blockIdx.x * 64, by = blockIdx.y, n0 = by * 64;

  if constexpr (!ABF){
    const float* A = (const float*)Av;
    #pragma unroll
    for (int i = 0; i < K/16; i++){
      int q = tid + i*256;
      int row = q / (K/4), c4 = q % (K/4);
      float4 a = make_float4(0.f,0.f,0.f,0.f);
      if (m0 + row < M) a = *(const float4*)&A[(size_t)(m0+row)*K + c4*4];
      *(uint2*)&At[row][c4*4] = make_uint2(packbf(a.x,a.y), packbf(a.z,a.w));
    }
  } else {
    const __hip_bfloat16* A = (const __hip_bfloat16*)Av;
    #pragma unroll
    for (int i = 0; i < K/32; i++){
      int q = tid + i*256;
      int row = q / (K/8), c8 = q % (K/8);
      uint4 u = make_uint4(0,0,0,0);
      if (m0 + row < M) u = *(const uint4*)&A[(size_t)(m0+row)*K + c8*8];
      *(uint4*)&At[row][c8*8] = u;
    }
  }
  #pragma unroll
  for (int i = 0; i < K/16; i++){
    int q = tid + i*256;
    int c = q & 63, k4 = q >> 6;
    float b0 = B[(size_t)(k4*4+0)*ldb + n0 + c];
    float b1 = B[(size_t)(k4*4+1)*ldb + n0 + c];
    float b2 = B[(size_t)(k4*4+2)*ldb + n0 + c];
    float b3 = B[(size_t)(k4*4+3)*ldb + n0 + c];
    *(uint2*)&Bt[c][k4*4] = make_uint2(packbf(b0,b1), packbf(b2,b3));
  }
  __syncthreads();

  f32x4 acc[2][2];
  #pragma unroll
  for (int i = 0; i < 2; i++)
    #pragma unroll
    for (int j = 0; j < 2; j++)
      #pragma unroll
      for (int r = 0; r < 4; r++) acc[i][j][r] = 0.f;

  const int rbase = mw*32, cbase = nw*32;
  const int fr = lane & 15, fg = lane >> 4;
  #pragma unroll
  for (int ks = 0; ks < K/32; ks++){
    short8v a0 = *(const short8v*)&At[rbase + fr     ][ks*32 + fg*8];
    short8v a1 = *(const short8v*)&At[rbase + 16 + fr][ks*32 + fg*8];
    short8v b0 = *(const short8v*)&Bt[cbase + fr     ][ks*32 + fg*8];
    short8v b1 = *(const short8v*)&Bt[cbase + 16 + fr][ks*32 + fg*8];
    acc[0][0] = __builtin_amdgcn_mfma_f32_16x16x32_bf16(a0, b0, acc[0][0], 0,0,0);
    acc[0][1] = __builtin_amdgcn_mfma_f32_16x16x32_bf16(a0, b1, acc[0][1], 0,0,0);
    acc[1][0] = __builtin_amdgcn_mfma_f32_16x16x32_bf16(a1, b0, acc[1][0], 0,0,0);
    acc[1][1] = __builtin_amdgcn_mfma_f32_16x16x32_bf16(a1, b1, acc[1][1], 0,0,0);
  }

  float alv[2], arv[2];
  #pragma unroll
  for (int nt = 0; nt < 2; nt++){
    int col = cbase + nt*16 + fr;
    alv[nt] = al[by*64 + col];
    arv[nt] = ar[by*64 + col];
  }
  #pragma unroll
  for (int mt = 0; mt < 2; mt++){
    #pragma unroll
    for (int r = 0; r < 4; r++){
      float pl = acc[mt][0][r]*alv[0] + acc[mt][1][r]*alv[1];
      float pr = acc[mt][0][r]*arv[0] + acc[mt][1][r]*arv[1];
      #pragma unroll
      for (int o = 1; o < 16; o <<= 1){ pl += __shfl_xor(pl, o); pr += __shfl_xor(pr, o); }
      if (fr == 0){
        int rl = rbase + mt*16 + fg*4 + r;
        elp[nw][rl] = pl; erp[nw][rl] = pr;
      }
    }
  }
  const int NN = H*64;
  #pragma unroll
  for (int mt = 0; mt < 2; mt++){
    #pragma unroll
    for (int r = 0; r < 4; r++){
      int row = m0 + rbase + mt*16 + fg*4 + r;
      if (row < M){
        #pragma unroll
        for (int nt = 0; nt < 2; nt++)
          Cbf[(size_t)row*NN + n0 + cbase + nt*16 + fr] = f2bf(acc[mt][nt][r]);
      }
    }
  }
  __syncthreads();
  if (tid < 64){
    int row = m0 + tid;
    if (row < M){
      el[(size_t)row*H + by] = elp[0][tid] + elp[1][tid];
      er[(size_t)row*H + by] = erp[0][tid] + erp[1][tid];
    }
  }
}

// ---------------- pure gather-aggregate, H=4 (layer 1), grid-stride, 32-bit addr ----------------
__global__ __launch_bounds__(256) void k_gath4(const uint4* __restrict__ fbase, // bf16 [N][256] as uint4[N*32]
      const float* __restrict__ w4, const int* __restrict__ row_start,
      const int* __restrict__ srcp, const float* __restrict__ bias,
      __hip_bfloat16* __restrict__ outb, int N, int nwaves){
  int wv = threadIdx.x >> 6, lane = threadIdx.x & 63;
  int g = lane >> 4, j = lane & 15, h = j >> 2;
  const unsigned jo2 = (unsigned)(j << 1);   // uint4 index within row (2 per lane)

  int n = blockIdx.x*4 + wv;
  if (n >= N) return;
  int rs = row_start[n], re = row_start[n+1];

  while (true){
    int deg = re - rs;
    int nn = n + nwaves;
    int rs_n = 0, re_n = 0;
    if (nn < N){ rs_n = row_start[nn]; re_n = row_start[nn+1]; }  // prefetch next node

    float acc[16];
    #pragma unroll
    for (int k = 0; k < 16; k++) acc[k] = 0.f;
    float Sacc = 0.f;

    int i = 0;
    int full = deg & ~15;          // unguarded 16-edge quads
    for (; i < full; i += 16){
      float wb[4]; uint4 u0[4], u1[4];
      #pragma unroll
      for (int k = 0; k < 4; k++){
        unsigned e = (unsigned)(rs + i + k*4 + g);
        int sb = srcp[e];
        wb[k] = w4[(e << 2) + h];
        unsigned fi = ((unsigned)sb << 5) + jo2;
        u0[k] = fbase[fi];
        u1[k] = fbase[fi + 1];
      }
      #pragma unroll
      for (int k = 0; k < 4; k++){
        float wk = wb[k];
        Sacc += wk;
        acc[0]  += bf_lo(u0[k].x)*wk; acc[1]  += bf_hi(u0[k].x)*wk;
        acc[2]  += bf_lo(u0[k].y)*wk; acc[3]  += bf_hi(u0[k].y)*wk;
        acc[4]  += bf_lo(u0[k].z)*wk; acc[5]  += bf_hi(u0[k].z)*wk;
        acc[6]  += bf_lo(u0[k].w)*wk; acc[7]  += bf_hi(u0[k].w)*wk;
        acc[8]  += bf_lo(u1[k].x)*wk; acc[9]  += bf_hi(u1[k].x)*wk;
        acc[10] += bf_lo(u1[k].y)*wk; acc[11] += bf_hi(u1[k].y)*wk;
        acc[12] += bf_lo(u1[k].z)*wk; acc[13] += bf_hi(u1[k].z)*wk;
        acc[14] += bf_lo(u1[k].w)*wk; acc[15] += bf_hi(u1[k].w)*wk;
      }
    }
    if (i < deg){                  // guarded tail (<=15 edges)
      float wb[4]; uint4 u0[4], u1[4];
      #pragma unroll
      for (int k = 0; k < 4; k++){
        int e = i + k*4 + g;
        wb[k] = 0.f;
        u0[k] = make_uint4(0,0,0,0); u1[k] = make_uint4(0,0,0,0);
        if (e < deg){
          unsigned ee = (unsigned)(rs + e);
          int sb = srcp[ee];
          wb[k] = w4[(ee << 2) + h];
          unsigned fi = ((unsigned)sb << 5) + jo2;
          u0[k] = fbase[fi];
          u1[k] = fbase[fi + 1];
        }
      }
      #pragma unroll
      for (int k = 0; k < 4; k++){
        float wk = wb[k];
        Sacc += wk;
        acc[0]  += bf_lo(u0[k].x)*wk; acc[1]  += bf_hi(u0[k].x)*wk;
        acc[2]  += bf_lo(u0[k].y)*wk; acc[3]  += bf_hi(u0[k].y)*wk;
        acc[4]  += bf_lo(u0[k].z)*wk; acc[5]  += bf_hi(u0[k].z)*wk;
        acc[6]  += bf_lo(u0[k].w)*wk; acc[7]  += bf_hi(u0[k].w)*wk;
        acc[8]  += bf_lo(u1[k].x)*wk; acc[9]  += bf_hi(u1[k].x)*wk;
        acc[10] += bf_lo(u1[k].y)*wk; acc[11] += bf_hi(u1[k].y)*wk;
        acc[12] += bf_lo(u1[k].z)*wk; acc[13] += bf_hi(u1[k].z)*wk;
        acc[14] += bf_lo(u1[k].w)*wk; acc[15] += bf_hi(u1[k].w)*wk;
      }
    }

    #pragma unroll
    for (int k = 0; k < 16; k++){
      acc[k] += __shfl_xor(acc[k], 16);
      acc[k] += __shfl_xor(acc[k], 32);
    }
    Sacc += __shfl_xor(Sacc, 16);
    Sacc += __shfl_xor(Sacc, 32);
    if (g == 0){
      float inv = (deg > 0 && Sacc > 0.f) ? 1.f / Sacc : 0.f;
      float4 b0 = *(const float4*)&bias[j*16 + 0];
      float4 b1 = *(const float4*)&bias[j*16 + 4];
      float4 b2 = *(const float4*)&bias[j*16 + 8];
      float4 b3 = *(const float4*)&bias[j*16 + 12];
      float v[16];
      v[0]=acc[0]*inv+b0.x;  v[1]=acc[1]*inv+b0.y;  v[2]=acc[2]*inv+b0.z;  v[3]=acc[3]*inv+b0.w;
      v[4]=acc[4]*inv+b1.x;  v[5]=acc[5]*inv+b1.y;  v[6]=acc[6]*inv+b1.z;  v[7]=acc[7]*inv+b1.w;
      v[8]=acc[8]*inv+b2.x;  v[9]=acc[9]*inv+b2.y;  v[10]=acc[10]*inv+b2.z; v[11]=acc[11]*inv+b2.w;
      v[12]=acc[12]*inv+b3.x; v[13]=acc[13]*inv+b3.y; v[14]=acc[14]*inv+b3.z; v[15]=acc[15]*inv+b3.w;
      #pragma unroll
      for (int k = 0; k < 16; k++) v[k] = fmaxf(v[k], 0.f);   // relu (layer 1)
      uint4 o0, o1;
      o0.x = packbf(v[0], v[1]);   o0.y = packbf(v[2], v[3]);
      o0.z = packbf(v[4], v[5]);   o0.w = packbf(v[6], v[7]);
      o1.x = packbf(v[8], v[9]);   o1.y = packbf(v[10], v[11]);
      o1.z = packbf(v[12], v[13]); o1.w = packbf(v[14], v[15]);
      uint4* op = (uint4*)outb + (size_t)n*32 + (j << 1);
      op[0] = o0; op[1] = o1;
    }

    if (nn >= N) break;
    n = nn; rs = rs_n; re = re_n;
  }
}

// ---------------- gather-aggregate, H=1 (layer 2), inline weights, fp32 out ----------------
__global__ __launch_bounds__(256) void k_gath1(const uint2* __restrict__ fbase, // bf16 [N][64] as uint2[N*16]
      const float* __restrict__ el2, const float* __restrict__ er2,
      const int* __restrict__ row_start, const int* __restrict__ srcp,
      const float* __restrict__ bias, float* __restrict__ out, int N, int nwaves){
  int wv = threadIdx.x >> 6, lane = threadIdx.x & 63;
  int g = lane >> 4, j = lane & 15;
  const unsigned jo = (unsigned)j;

  int n = blockIdx.x*4 + wv;
  if (n >= N) return;
  int rs = row_start[n], re = row_start[n+1];

  while (true){
    int deg = re - rs;
    int nn = n + nwaves;
    int rs_n = 0, re_n = 0;
    if (nn < N){ rs_n = row_start[nn]; re_n = row_start[nn+1]; }

    float ern = er2[n];
    float acc[4] = {0.f, 0.f, 0.f, 0.f};
    float Sacc = 0.f;

    int i = 0;
    int full = deg & ~15;
    for (; i < full; i += 16){
      float wb[4]; uint2 u[4];
      #pragma unroll
      for (int k = 0; k < 4; k++){
        unsigned e = (unsigned)(rs + i + k*4 + g);
        int sb = srcp[e];                       // broadcast within 16-lane group
        float x = el2[sb] + ern;                // broadcast
        x = x > 0.f ? x : 0.2f*x;
        wb[k] = __expf(x);
        u[k] = fbase[((unsigned)sb << 4) + jo];
      }
      #pragma unroll
      for (int k = 0; k < 4; k++){
        float wk = wb[k];
        Sacc += wk;
        acc[0] += bf_lo(u[k].x)*wk; acc[1] += bf_hi(u[k].x)*wk;
        acc[2] += bf_lo(u[k].y)*wk; acc[3] += bf_hi(u[k].y)*wk;
      }
    }
    if (i < deg){
      float wb[4]; uint2 u[4];
      #pragma unroll
      for (int k = 0; k < 4; k++){
        int e = i + k*4 + g;
        wb[k] = 0.f;
        u[k] = make_uint2(0,0);
        if (e < deg){
          unsigned ee = (unsigned)(rs + e);
          int sb = srcp[ee];
          float x = el2[sb] + ern;
          x = x > 0.f ? x : 0.2f*x;
          wb[k] = __expf(x);
          u[k] = fbase[((unsigned)sb << 4) + jo];
        }
      }
      #pragma unroll
      for (int k = 0; k < 4; k++){
        float wk = wb[k];
        Sacc += wk;
        acc[0] += bf_lo(u[k].x)*wk; acc[1] += bf_hi(u[k].x)*wk;
        acc[2] += bf_lo(u[k].y)*wk; acc[3] += bf_hi(u[k].y)*wk;
      }
    }

    #pragma unroll
    for (int k = 0; k < 4; k++){
      acc[k] += __shfl_xor(acc[k], 16);
      acc[k] += __shfl_xor(acc[k], 32);
    }
    Sacc += __shfl_xor(Sacc, 16);
    Sacc += __shfl_xor(Sacc, 32);
    if (g == 0){
      float inv = (deg > 0 && Sacc > 0.f) ? 1.f / Sacc : 0.f;
      float4 b = *(const float4*)&bias[j*4];
      float4 o;
      o.x = acc[0]*inv + b.x; o.y = acc[1]*inv + b.y;
      o.z = acc[2]*inv + b.z; o.w = acc[3]*inv + b.w;
      *(float4*)&out[(size_t)n*64 + j*4] = o;
    }

    if (nn >= N) break;
    n = nn; rs = rs_n; re = re_n;
  }
}

// ---------------- launch ----------------
extern "C" void kernel_launch(void* const* d_in, const int* in_sizes, int n_in,
                              void* d_out, int out_size, void* d_ws, size_t ws_size,
                              hipStream_t stream) {
  const float* emb = (const float*)d_in[0];
  const int*   src = (const int*)d_in[1];
  const int*   dst = (const int*)d_in[2];
  const float* W1  = (const float*)d_in[3];
  const float* al1 = (const float*)d_in[4];
  const float* ar1 = (const float*)d_in[5];
  const float* b1  = (const float*)d_in[6];
  const float* W2  = (const float*)d_in[7];
  const float* al2 = (const float*)d_in[8];
  const float* ar2 = (const float*)d_in[9];
  const float* b2  = (const float*)d_in[10];
  float* out = (float*)d_out;

  const int N = in_sizes[0] / 128;
  const int E = in_sizes[1];

  char* p = (char*)d_ws;
  auto alloc = [&](size_t bytes) -> void* {
    void* r = (void*)p; p += (bytes + 255) & ~(size_t)255; return r;
  };
  __hip_bfloat16* feat1b = (__hip_bfloat16*)alloc((size_t)N*256*2);
  __hip_bfloat16* h1b    = (__hip_bfloat16*)alloc((size_t)N*256*2);
  __hip_bfloat16* feat2b = (__hip_bfloat16*)alloc((size_t)N*64*2);
  float* el1             = (float*)alloc((size_t)N*4*4);
  float* er1             = (float*)alloc((size_t)N*4*4);
  float* el2             = (float*)alloc((size_t)N*4);
  float* er2             = (float*)alloc((size_t)N*4);
  int*   deg             = (int*)alloc((size_t)N*4);
  int*   row_start       = (int*)alloc((size_t)(N+1)*4);
  int*   cursor          = (int*)alloc((size_t)N*4);
  int*   blocksum        = (int*)alloc((size_t)DIV_UP(N,1024)*4);
  int*   srcp            = (int*)alloc((size_t)E*4);
  float* w4              = (float*)alloc((size_t)E*16);

  const int nb = DIV_UP(N, 1024);
  const int gblocks = min(DIV_UP(N, 4), 2048);
  const int nwaves  = gblocks * 4;
  const int gemmBlocks = DIV_UP(N, 64);
  const int cntBlocks  = DIV_UP(E, 256);

  hipMemsetAsync(deg, 0, (size_t)N*4, stream);

  // GEMM1 (layer-1 features + el1/er1) fused with degree count (independent work)
  k_gemm1_count<<<gemmBlocks + cntBlocks, 256, 0, stream>>>(
      emb, W1, (unsigned short*)feat1b, al1, ar1, el1, er1, N,
      dst, deg, E, gemmBlocks);

  k_scan1<<<nb, 256, 0, stream>>>(deg, blocksum, N);
  k_scan3<<<nb, 256, 0, stream>>>(deg, blocksum, nb, row_start, cursor, N);
  k_fillw4<<<DIV_UP(E,256), 256, 0, stream>>>(dst, src, cursor, srcp,
      (const float4*)el1, (const float4*)er1, (float4*)w4, E);

  k_gath4<<<gblocks, 256, 0, stream>>>((const uint4*)feat1b, w4, row_start,
                                       srcp, b1, h1b, N, nwaves);
  // Layer 2
  k_gemm_mfma<256,1,true><<<dim3(DIV_UP(N,64), 1), 256, 0, stream>>>(
      h1b, W2, 64, (unsigned short*)feat2b, al2, ar2, el2, er2, N);
  k_gath1<<<gblocks, 256, 0, stream>>>((const uint2*)feat2b, el2, er2,
                                       row_start, srcp, b2, out, N, nwaves);
}